// Round 14
// baseline (849.245 us; speedup 1.0000x reference)
//
#include <hip/hip_runtime.h>
#include <math.h>

#define NNODE 20000
#define NEDGE 80000
#define NGRAPH 64

// ---------------- workspace layout (float offsets) ----------------
#define OFF_TANH  656
#define OFF_CNT   660
#define OFF_GSUM  664
#define OFF_HIST  7680
#define OFF_OFFS  9728
#define OFF_CUR   11784
#define OFF_EATTR 14336
#define OFF_RBUF  1294336
#define OFF_EINFO 1374336
#define OFF_X0    1694336
#define OFF_Y1    2014336
#define OFF_Y2    5214336
#define OFF_X1    7774336
#define OFF_X2    10334336
#define OFF_TAB   12414336

// w3j table offsets
#define T000 0
#define T110 1
#define T220 10
#define T330 35
#define T011 84
#define T101 93
#define T111 102
#define T121 129
#define T211 174
#define T231 219
#define T321 324
#define T221 429
#define T331 504

#define INV_SQRT_NEIGH 0.5129891760425771f
#define SQRT2F 1.4142135623730951f

struct TabD { int l1,l2,l3,off; };
constexpr TabD HTABS[13] = {
  {0,0,0,T000},{1,1,0,T110},{2,2,0,T220},{3,3,0,T330},
  {0,1,1,T011},{1,0,1,T101},{1,1,1,T111},{1,2,1,T121},
  {2,1,1,T211},{2,3,1,T231},{3,2,1,T321},{2,2,1,T221},{3,3,1,T331}
};

struct CoreD { short a_off, b_off; short l1,l2,l3; short tab; short coff; short m1; };
struct PathD { short core; short wofs, wend, ooff; short mo, lo; float pw; };

// ---- conv1: SH (x) SH -> GATE1_IN ----
constexpr CoreD HCORES1[13] = {
  {0,0, 0,0,0, T000, 0, 1},
  {0,1, 0,1,1, T011, 1, 1},
  {1,0, 1,0,1, T101, 4, 1},
  {1,1, 1,1,0, T110, 7, 1},
  {1,1, 1,1,1, T111, 8, 1},
  {1,4, 1,2,1, T121, 11, 1},
  {4,1, 2,1,1, T211, 14, 1},
  {4,4, 2,2,0, T220, 17, 1},
  {4,4, 2,2,1, T221, 18, 1},
  {4,9, 2,3,1, T231, 21, 1},
  {9,4, 3,2,1, T321, 24, 1},
  {9,9, 3,3,0, T330, 27, 1},
  {9,9, 3,3,1, T331, 28, 1}
};
#define PWR 0.7071067811865476f
constexpr PathD HPATHS1[21] = {
  {0,  0, 16,  0,16,0,0.5f},
  {0, 16, 24, 32, 8,0,0.5f},
  {0, 24, 32, 48, 8,0,0.5f},
  {1, 32, 48, 64,16,1,PWR},
  {2, 48, 64, 64,16,1,PWR},
  {3, 64, 80,  0,16,0,0.5f},
  {3, 80, 88, 32, 8,0,0.5f},
  {3, 88, 96, 48, 8,0,0.5f},
  {4, 96,112,112,16,1,1.0f},
  {5,112,128, 64,16,1,PWR},
  {6,128,144, 64,16,1,PWR},
  {7,144,160,  0,16,0,0.5f},
  {7,160,168, 32, 8,0,0.5f},
  {7,168,176, 48, 8,0,0.5f},
  {8,176,192,112,16,1,1.0f},
  {9,192,208, 64,16,1,PWR},
  {10,208,224,64,16,1,PWR},
  {11,224,240, 0,16,0,0.5f},
  {11,240,248,32, 8,0,0.5f},
  {11,248,256,48, 8,0,0.5f},
  {12,256,272,112,16,1,1.0f}
};

// ---- conv2: GATE1_OUT (x) SH -> GATE2_IN ----
constexpr CoreD HCORES2[12] = {
  {0,0,  0,0,0, T000, 0,   16},
  {0,1,  0,1,1, T011, 16,  16},
  {16,0, 0,0,0, T000, 64,  16},
  {16,1, 0,1,1, T011, 80,  16},
  {32,0, 1,0,1, T101, 128, 16},
  {32,1, 1,1,0, T110, 176, 16},
  {32,1, 1,1,1, T111, 192, 16},
  {32,4, 1,2,1, T121, 240, 16},
  {80,0, 1,0,1, T101, 288, 16},
  {80,1, 1,1,0, T110, 336, 16},
  {80,1, 1,1,1, T111, 352, 16},
  {80,4, 1,2,1, T121, 400, 16}
};
#define PA 0.14433756729740643f
#define PB 0.25f
#define PC 0.19364916731037085f
constexpr PathD HPATHS2[20] = {
  {0,   0, 256,  0,16,0,PA},
  {0, 256, 352, 32, 6,0,PA},
  {0, 352, 448, 44, 6,0,PA},
  {1, 448, 640, 56,12,1,PC},
  {2, 640, 896,  0,16,0,PA},
  {2, 896, 992, 32, 6,0,PA},
  {2, 992,1088, 44, 6,0,PA},
  {3,1088,1280, 56,12,1,PC},
  {4,1280,1472, 56,12,1,PC},
  {5,1472,1728,  0,16,0,PA},
  {5,1728,1824, 32, 6,0,PA},
  {5,1824,1920, 44, 6,0,PA},
  {6,1920,2112, 92,12,1,PB},
  {7,2112,2304, 56,12,1,PC},
  {8,2304,2496, 92,12,1,PB},
  {9,2496,2752, 16,16,0,PB},
  {9,2752,2848, 38, 6,0,PB},
  {9,2848,2944, 50, 6,0,PB},
  {10,2944,3136,56,12,1,PC},
  {11,3136,3328,92,12,1,PB}
};

// ---- conv3: GATE2_OUT (x) SH -> OUT_FINAL ----
constexpr CoreD HCORES3[3] = {
  {0,0,  0,0,0, T000, 0,  16},
  {16,0, 0,0,0, T000, 16, 16},
  {32,1, 1,1,0, T110, 32, 12}
};
#define PD 0.15075567228888181f
constexpr PathD HPATHS3[3] = {
  {0, 0,16, 0,1,0,PD},
  {1,16,32, 0,1,0,PD},
  {2,32,44, 0,1,0,PD}
};

// ================= compile-time w3j tables (exact port of reference) =================
constexpr double FACT[9] = {1.0,1.0,2.0,6.0,24.0,120.0,720.0,5040.0,40320.0};

constexpr double csqrt_(double x){
  if(x<=0.0) return 0.0;
  double g = (x<1.0)? 1.0 : x;
  for(int i=0;i<40;i++) g = 0.5*(g + x/g);
  return g;
}

constexpr double cw3j_(int j1,int j2,int j3,int m1,int m2,int m3){
  if(m1+m2+m3!=0) return 0.0;
  int t1=j2-m1-j3, t2=j1+m2-j3, t3=j1+j2-j3, t4=j1-m1, t5=j2+m2;
  int tmin=t1>0?t1:0; if(t2>tmin) tmin=t2;
  int tmax=t3<t4?t3:t4; if(t5<tmax) tmax=t5;
  if(tmin>tmax) return 0.0;
  double s=0.0;
  for(int t=tmin;t<=tmax;++t){
    double d=FACT[t]*FACT[t-t1]*FACT[t-t2]*FACT[t3-t]*FACT[t4-t]*FACT[t5-t];
    s += ((t&1)? -1.0:1.0)/d;
  }
  double tri=FACT[j1+j2-j3]*FACT[j1-j2+j3]*FACT[-j1+j2+j3]/FACT[j1+j2+j3+1];
  double nrm=csqrt_(tri*FACT[j1+m1]*FACT[j1-m1]*FACT[j2+m2]*FACT[j2-m2]*FACT[j3+m3]*FACT[j3-m3]);
  return (((j1-j2-m3)&1)? -1.0:1.0)*nrm*s;
}

constexpr int curow_(int l,int i,int* a,double* re,double* im){
  const double is2=0.7071067811865475;
  int m=i-l;
  if(m==0){ a[0]=l; re[0]=1.0; im[0]=0.0; return 1; }
  if(m>0){
    a[0]=l+m; re[0]=((m&1)? -is2:is2); im[0]=0.0;
    a[1]=l-m; re[1]=is2; im[1]=0.0; return 2;
  }
  int mm=-m;
  a[0]=l-mm; re[0]=0.0; im[0]=is2;
  a[1]=l+mm; re[1]=0.0; im[1]=((mm&1)? is2:-is2);
  return 2;
}

constexpr float cw3j_elem_(int l1,int l2,int l3,int i,int j,int k){
  int aa[2]={0,0},bb[2]={0,0},cc[2]={0,0};
  double ar[2]={0,0},ai[2]={0,0},br[2]={0,0},bi[2]={0,0},cr[2]={0,0},ci[2]={0,0};
  int na=curow_(l1,i,aa,ar,ai);
  int nb=curow_(l2,j,bb,br,bi);
  int nc=curow_(l3,k,cc,cr,ci);
  double accr=0.0, acci=0.0;
  for(int x=0;x<na;x++)for(int y=0;y<nb;y++)for(int w=0;w<nc;w++){
    double wv=cw3j_(l1,l2,l3, aa[x]-l1, bb[y]-l2, cc[w]-l3);
    if(wv==0.0) continue;
    double pr=ar[x]*br[y]-ai[x]*bi[y];
    double pi=ar[x]*bi[y]+ai[x]*br[y];
    double qr=pr*cr[w]-pi*ci[w];
    double qi=pr*ci[w]+pi*cr[w];
    accr+=qr*wv; acci+=qi*wv;
  }
  int Lm=(l1+l2+l3)&3;  // Re((-i)^L * acc)
  double res = (Lm==0)? accr : (Lm==1)? acci : (Lm==2)? -accr : -acci;
  return (float)res;
}

struct WApart { float v[429]; };
constexpr WApart gen_wa_(){
  WApart o{};
  for(int t=0;t<11;t++){
    int l1=HTABS[t].l1,l2=HTABS[t].l2,l3=HTABS[t].l3;
    int n2=2*l2+1,n3=2*l3+1;
    int tot=(2*l1+1)*n2*n3;
    for(int z=0;z<tot;z++){
      int i=z/(n2*n3), j=(z/n3)%n2, k=z%n3;
      o.v[HTABS[t].off+z]=cw3j_elem_(l1,l2,l3,i,j,k);
    }
  }
  return o;
}
struct WBpart { float v[222]; };
constexpr WBpart gen_wb_(){
  WBpart o{};
  for(int t=11;t<13;t++){
    int l1=HTABS[t].l1,l2=HTABS[t].l2,l3=HTABS[t].l3;
    int n2=2*l2+1,n3=2*l3+1;
    int tot=(2*l1+1)*n2*n3;
    for(int z=0;z<tot;z++){
      int i=z/(n2*n3), j=(z/n3)%n2, k=z%n3;
      o.v[HTABS[t].off-429+z]=cw3j_elem_(l1,l2,l3,i,j,k);
    }
  }
  return o;
}
constexpr WApart WAC = gen_wa_();
constexpr WBpart WBC = gen_wb_();
struct W3Full { float v[651]; };
constexpr W3Full gen_wfull_(){
  W3Full f{};
  for(int i=0;i<429;i++) f.v[i]=WAC.v[i];
  for(int i=0;i<222;i++) f.v[429+i]=WBC.v[i];
  return f;
}
__constant__ W3Full W3JC = gen_wfull_();

// ================= compile-time per-j path-weight scale =================
template<int NW> struct PwArr { float v[NW]; };
template<int NW,int NP>
constexpr PwArr<NW> gen_pw_(const PathD (&P)[NP]){
  PwArr<NW> a{};
  for(int p=0;p<NP;p++)
    for(int j=P[p].wofs;j<P[p].wend;j++) a.v[j]=P[p].pw;
  return a;
}
__constant__ PwArr<272>  PWC1 = gen_pw_<272>(HPATHS1);
__constant__ PwArr<3328> PWC2 = gen_pw_<3328>(HPATHS2);
__constant__ PwArr<44>   PWC3 = gen_pw_<44>(HPATHS3);

// ================= compile-time column-based apply metadata + table permutation =================
struct OutSeg { int mult, l; };
constexpr OutSeg OSEG1[8] = {{16,0},{16,0},{8,0},{8,0},{8,0},{8,0},{16,1},{16,1}};
constexpr OutSeg OSEG2[8] = {{16,0},{16,0},{6,0},{6,0},{6,0},{6,0},{12,1},{12,1}};
constexpr OutSeg OSEG3[1] = {{1,0}};

struct Ent2 { int jb, cb, nu; };  // weights at T[jb .. jb+nu) (new layout); core block cb (u-major)
template<int NCOL,int NENT,int NW> struct ColMetaT {
  int cidx[NCOL+1];
  int obase[NCOL];
  int n3c[NCOL];
  Ent2 ent[NENT];
  int newj[NW];     // old j -> new j (used by table writer)
};

template<int NCOL,int NENT,int NW,int NSEG,int NP,int NC>
constexpr ColMetaT<NCOL,NENT,NW> gen_colmeta_(const OutSeg (&S)[NSEG], const PathD (&P)[NP], const CoreD (&C)[NC]){
  ColMetaT<NCOL,NENT,NW> m{};
  int col=0, cnt=0, o=0, nb=0;
  for(int s=0;s<NSEG;s++){
    int n3=2*S[s].l+1;
    for(int wc=0;wc<S[s].mult;wc++){
      m.cidx[col]=cnt;
      int ob=o+wc*n3;
      m.obase[col]=ob;
      m.n3c[col]=n3;
      for(int p=0;p<NP;p++){
        PathD pd=P[p];
        int pn3=2*pd.lo+1;
        if(pn3!=n3) continue;
        int rel=ob-pd.ooff;
        if(rel<0||rel>=pd.mo*pn3) continue;
        int w=rel/pn3;
        CoreD cd=C[pd.core];
        int m1=cd.m1;
        m.ent[cnt]=Ent2{nb,(int)cd.coff,m1};
        for(int u=0;u<m1;u++) m.newj[pd.wofs + w + u*pd.mo]=nb+u;
        nb+=m1;
        cnt++;
      }
      col++;
    }
    o+=S[s].mult*n3;
  }
  m.cidx[col]=cnt;
  return m;
}

__constant__ ColMetaT<96,272,272>  CMETA1 = gen_colmeta_<96,272,272>(OSEG1, HPATHS1, HCORES1);
__constant__ ColMetaT<80,208,3328> CMETA2 = gen_colmeta_<80,208,3328>(OSEG2, HPATHS2, HCORES2);
__constant__ ColMetaT< 1,  3,  44> CMETA3 = gen_colmeta_< 1,  3,  44>(OSEG3, HPATHS3, HCORES3);

// ================= core-contraction metadata =================
struct CItem { short aoff, boff, n1, n2, cofs, jstep, woff, pad; };
struct CArr1 { CItem it[31]; };
constexpr CArr1 gen_c1_(){
  CArr1 a{}; int s=0;
  for(int cn=0;cn<13;cn++){
    CoreD cd=HCORES1[cn];
    int n1=2*cd.l1+1,n2=2*cd.l2+1,n3=2*cd.l3+1;
    for(int k=0;k<n3;k++){
      a.it[s]=CItem{cd.a_off,cd.b_off,(short)n1,(short)n2,(short)(cd.tab+k),(short)n3,(short)(cd.coff+k),0};
      s++;
    }
  }
  return a;
}
__constant__ CArr1 CIT1 = gen_c1_();

struct Fam { short b_off, tab, n1, n2, n3, goff; };
constexpr Fam GF2[6]={
  {0,T000,1,1,1,0},{1,T011,1,3,3,1},{0,T101,3,1,3,4},
  {1,T110,3,3,1,13},{1,T111,3,3,3,16},{4,T121,3,5,3,25}};
constexpr Fam GF3[2]={{0,T000,1,1,1,0},{1,T110,3,3,1,1}};
struct CoreG { short fam,a_off,m1,coff; };
constexpr CoreG CG2[12]={
  {0,0,16,0},{1,0,16,16},{0,16,16,64},{1,16,16,80},
  {2,32,16,128},{3,32,16,176},{4,32,16,192},{5,32,16,240},
  {2,80,16,288},{3,80,16,336},{4,80,16,352},{5,80,16,400}};
constexpr CoreG CG3[3]={{0,0,16,0},{0,16,16,16},{1,32,12,32}};

struct GItem { short boff, cofs, n2, jstep; };
template<int NG> struct GArrT { GItem it[NG]; };
template<int NG,int NF>
constexpr GArrT<NG> gen_g_(const Fam (&F)[NF]){
  GArrT<NG> a{}; int s=0;
  for(int f=0;f<NF;f++){
    for(int i=0;i<F[f].n1;i++)for(int k=0;k<F[f].n3;k++){
      a.it[s]=GItem{F[f].b_off,(short)(F[f].tab + i*F[f].n2*F[f].n3 + k),F[f].n2,F[f].n3};
      s++;
    }
  }
  return a;
}
__constant__ GArrT<34> GIT2=gen_g_<34>(GF2);
__constant__ GArrT<4>  GIT3=gen_g_<4>(GF3);

struct OItem { short aoff, gofs, n1, n3, woff, pad; };
template<int NO> struct OArrT { OItem it[NO]; };
template<int NO,int NC,int NF>
constexpr OArrT<NO> gen_o_(const CoreG (&C)[NC], const Fam (&F)[NF]){
  OArrT<NO> a{}; int s=0;
  for(int cn=0;cn<NC;cn++){
    Fam f=F[C[cn].fam];
    for(int k=0;k<f.n3;k++)for(int u=0;u<C[cn].m1;u++){
      a.it[s]=OItem{(short)(C[cn].a_off+u*f.n1),(short)(f.goff+k),f.n1,f.n3,
                    (short)(C[cn].coff+k*C[cn].m1+u),0};
      s++;
    }
  }
  return a;
}
__constant__ OArrT<448> OIT2=gen_o_<448,12,6>(CG2,GF2);
__constant__ OArrT<44>  OIT3=gen_o_<44,3,2>(CG3,GF3);

// ---------------- unrolled apply column processors ----------------
// conv1: nu==1 entries, weights contiguous at ep[0].jb
template<int CNT,int N3,int NCOLS>
__device__ __forceinline__ void apply1_col(const Ent2* __restrict__ ep, const float* __restrict__ T0,
    const float* __restrict__ crb, float fr, float&a0,float&a1,float&a2){
  const float* tja=T0+ep[0].jb;
  float wv[CNT];
  #pragma unroll
  for(int t=0;t<CNT;t++){
    float w0=tja[t], w1=tja[t+NCOLS];
    wv[t]=w0+fr*(w1-w0);
  }
  #pragma unroll
  for(int t=0;t<CNT;t++){
    const float* cr=crb+ep[t].cb;
    a0=fmaf(wv[t],cr[0],a0);
    if constexpr(N3==3){ a1=fmaf(wv[t],cr[1],a1); a2=fmaf(wv[t],cr[2],a2); }
  }
}
__device__ __forceinline__ void apply1_dyn(const Ent2* __restrict__ ep, int cnt, int n3,
    const float* __restrict__ T0, const float* __restrict__ crb, float fr, int NCOLS,
    float&a0,float&a1,float&a2){
  const float* tja=T0+ep[0].jb;
  for(int t=0;t<cnt;t++){
    float w0=tja[t], w1=tja[t+NCOLS];
    float w=w0+fr*(w1-w0);
    const float* cr=crb+ep[t].cb;
    a0=fmaf(w,cr[0],a0);
    if(n3==3){ a1=fmaf(w,cr[1],a1); a2=fmaf(w,cr[2],a2); }
  }
}

// conv2 PAIR apply: one thread serves 2 edges for a column; when both edges
// share the table row (r-sorted: ~90% of pairs) w0/w1 loads are issued ONCE.
// Per-edge arithmetic (values, lerp, fmaf order) identical to the 1-edge
// version -> bit-identical outputs.
template<int CNT,int N3,int NCOLS>
__device__ __forceinline__ void apply2p_col(const Ent2* __restrict__ ep,
    const float* __restrict__ Ta, const float* __restrict__ Tb,
    const float* __restrict__ cra, const float* __restrict__ crbp,
    float fra, float frb, bool srow,
    float&a0a,float&a1a,float&a2a,float&a0b,float&a1b,float&a2b){
  #pragma unroll
  for(int t=0;t<CNT;t++){
    const float* ca=cra+ep[t].cb;
    const float* cb=crbp+ep[t].cb;
    const float* tja=Ta+ep[t].jb;
    const float* tjb=Tb+ep[t].jb;
    #pragma unroll
    for(int uu=0;uu<16;uu+=4){
      float4 w0=*(const float4*)(tja+uu);
      float4 w1=*(const float4*)(tja+NCOLS+uu);
      float4 w0b,w1b;
      if(srow){ w0b=w0; w1b=w1; }
      else { w0b=*(const float4*)(tjb+uu); w1b=*(const float4*)(tjb+NCOLS+uu); }
      float w;
      if constexpr(N3==1){
        float4 cva=*(const float4*)(ca+uu);
        float4 cvb=*(const float4*)(cb+uu);
        w=w0.x+fra*(w1.x-w0.x); a0a=fmaf(w,cva.x,a0a);
        w=w0.y+fra*(w1.y-w0.y); a0a=fmaf(w,cva.y,a0a);
        w=w0.z+fra*(w1.z-w0.z); a0a=fmaf(w,cva.z,a0a);
        w=w0.w+fra*(w1.w-w0.w); a0a=fmaf(w,cva.w,a0a);
        w=w0b.x+frb*(w1b.x-w0b.x); a0b=fmaf(w,cvb.x,a0b);
        w=w0b.y+frb*(w1b.y-w0b.y); a0b=fmaf(w,cvb.y,a0b);
        w=w0b.z+frb*(w1b.z-w0b.z); a0b=fmaf(w,cvb.z,a0b);
        w=w0b.w+frb*(w1b.w-w0b.w); a0b=fmaf(w,cvb.w,a0b);
      } else {
        float4 c0a=*(const float4*)(ca+uu);
        float4 c1a=*(const float4*)(ca+16+uu);
        float4 c2a=*(const float4*)(ca+32+uu);
        w=w0.x+fra*(w1.x-w0.x); a0a=fmaf(w,c0a.x,a0a); a1a=fmaf(w,c1a.x,a1a); a2a=fmaf(w,c2a.x,a2a);
        w=w0.y+fra*(w1.y-w0.y); a0a=fmaf(w,c0a.y,a0a); a1a=fmaf(w,c1a.y,a1a); a2a=fmaf(w,c2a.y,a2a);
        w=w0.z+fra*(w1.z-w0.z); a0a=fmaf(w,c0a.z,a0a); a1a=fmaf(w,c1a.z,a1a); a2a=fmaf(w,c2a.z,a2a);
        w=w0.w+fra*(w1.w-w0.w); a0a=fmaf(w,c0a.w,a0a); a1a=fmaf(w,c1a.w,a1a); a2a=fmaf(w,c2a.w,a2a);
        float4 c0b=*(const float4*)(cb+uu);
        float4 c1b=*(const float4*)(cb+16+uu);
        float4 c2b=*(const float4*)(cb+32+uu);
        w=w0b.x+frb*(w1b.x-w0b.x); a0b=fmaf(w,c0b.x,a0b); a1b=fmaf(w,c1b.x,a1b); a2b=fmaf(w,c2b.x,a2b);
        w=w0b.y+frb*(w1b.y-w0b.y); a0b=fmaf(w,c0b.y,a0b); a1b=fmaf(w,c1b.y,a1b); a2b=fmaf(w,c2b.y,a2b);
        w=w0b.z+frb*(w1b.z-w0b.z); a0b=fmaf(w,c0b.z,a0b); a1b=fmaf(w,c1b.z,a1b); a2b=fmaf(w,c2b.z,a2b);
        w=w0b.w+frb*(w1b.w-w0b.w); a0b=fmaf(w,c0b.w,a0b); a1b=fmaf(w,c1b.w,a1b); a2b=fmaf(w,c2b.w,a2b);
      }
    }
  }
}
__device__ __forceinline__ void apply2p_dyn(const Ent2* __restrict__ ep, int cnt, int n3,
    const float* __restrict__ Ta, const float* __restrict__ Tb,
    const float* __restrict__ cra, const float* __restrict__ crbp,
    float fra, float frb, bool srow, int NCOLS,
    float&a0a,float&a1a,float&a2a,float&a0b,float&a1b,float&a2b){
  for(int t=0;t<cnt;t++){
    const float* ca=cra+ep[t].cb;
    const float* cb=crbp+ep[t].cb;
    const float* tja=Ta+ep[t].jb;
    const float* tjb=Tb+ep[t].jb;
    #pragma unroll
    for(int uu=0;uu<16;uu+=4){
      float4 w0=*(const float4*)(tja+uu);
      float4 w1=*(const float4*)(tja+NCOLS+uu);
      float4 w0b,w1b;
      if(srow){ w0b=w0; w1b=w1; }
      else { w0b=*(const float4*)(tjb+uu); w1b=*(const float4*)(tjb+NCOLS+uu); }
      float w;
      if(n3==1){
        float4 cva=*(const float4*)(ca+uu);
        float4 cvb=*(const float4*)(cb+uu);
        w=w0.x+fra*(w1.x-w0.x); a0a=fmaf(w,cva.x,a0a);
        w=w0.y+fra*(w1.y-w0.y); a0a=fmaf(w,cva.y,a0a);
        w=w0.z+fra*(w1.z-w0.z); a0a=fmaf(w,cva.z,a0a);
        w=w0.w+fra*(w1.w-w0.w); a0a=fmaf(w,cva.w,a0a);
        w=w0b.x+frb*(w1b.x-w0b.x); a0b=fmaf(w,cvb.x,a0b);
        w=w0b.y+frb*(w1b.y-w0b.y); a0b=fmaf(w,cvb.y,a0b);
        w=w0b.z+frb*(w1b.z-w0b.z); a0b=fmaf(w,cvb.z,a0b);
        w=w0b.w+frb*(w1b.w-w0b.w); a0b=fmaf(w,cvb.w,a0b);
      } else {
        float4 c0a=*(const float4*)(ca+uu);
        float4 c1a=*(const float4*)(ca+16+uu);
        float4 c2a=*(const float4*)(ca+32+uu);
        w=w0.x+fra*(w1.x-w0.x); a0a=fmaf(w,c0a.x,a0a); a1a=fmaf(w,c1a.x,a1a); a2a=fmaf(w,c2a.x,a2a);
        w=w0.y+fra*(w1.y-w0.y); a0a=fmaf(w,c0a.y,a0a); a1a=fmaf(w,c1a.y,a1a); a2a=fmaf(w,c2a.y,a2a);
        w=w0.z+fra*(w1.z-w0.z); a0a=fmaf(w,c0a.z,a0a); a1a=fmaf(w,c1a.z,a1a); a2a=fmaf(w,c2a.z,a2a);
        w=w0.w+fra*(w1.w-w0.w); a0a=fmaf(w,c0a.w,a0a); a1a=fmaf(w,c1a.w,a1a); a2a=fmaf(w,c2a.w,a2a);
        float4 c0b=*(const float4*)(cb+uu);
        float4 c1b=*(const float4*)(cb+16+uu);
        float4 c2b=*(const float4*)(cb+32+uu);
        w=w0b.x+frb*(w1b.x-w0b.x); a0b=fmaf(w,c0b.x,a0b); a1b=fmaf(w,c1b.x,a1b); a2b=fmaf(w,c2b.x,a2b);
        w=w0b.y+frb*(w1b.y-w0b.y); a0b=fmaf(w,c0b.y,a0b); a1b=fmaf(w,c1b.y,a1b); a2b=fmaf(w,c2b.y,a2b);
        w=w0b.z+frb*(w1b.z-w0b.z); a0b=fmaf(w,c0b.z,a0b); a1b=fmaf(w,c1b.z,a1b); a2b=fmaf(w,c2b.z,a2b);
        w=w0b.w+frb*(w1b.w-w0b.w); a0b=fmaf(w,c0b.w,a0b); a1b=fmaf(w,c1b.w,a1b); a2b=fmaf(w,c2b.w,a2b);
      }
    }
  }
}

// ---------------- register-tiled table GEMM with GROUP-8 prefetch ----------------
__device__ __forceinline__ void table_gemm2(const float* __restrict__ W2, float* __restrict__ tab,
    int NCOLS, float scale, const float* __restrict__ PW, const int* __restrict__ NJ,
    int jb, const float (*__restrict__ sh_h)[8], int r0, int R){
  float acc[8][2];
  #pragma unroll
  for(int k=0;k<8;k++){ acc[k][0]=0.0f; acc[k][1]=0.0f; }
  const float* w2p=W2+jb;
  float2 cur[8], nxt[8];
  #pragma unroll
  for(int i=0;i<8;i++) cur[i]=*(const float2*)(w2p+(size_t)i*NCOLS);
  for(int g=0; g<256; g+=8){
    int gn=g+8;
    #pragma unroll
    for(int i=0;i<8;i++){
      int c=(gn+i<256)?(gn+i):255;
      nxt[i]=*(const float2*)(w2p+(size_t)c*NCOLS);
    }
    #pragma unroll
    for(int i=0;i<8;i++){
      int c=g+i;
      float h[8];
      *(float4*)&h[0]=*(const float4*)&sh_h[c][0];
      *(float4*)&h[4]=*(const float4*)&sh_h[c][4];
      #pragma unroll
      for(int k=0;k<8;k++){
        acc[k][0]=fmaf(h[k],cur[i].x,acc[k][0]);
        acc[k][1]=fmaf(h[k],cur[i].y,acc[k][1]);
      }
    }
    #pragma unroll
    for(int i=0;i<8;i++) cur[i]=nxt[i];
  }
  #pragma unroll
  for(int u=0;u<2;u++){
    float cs=scale*PW[jb+u];
    int jn=NJ[jb+u];
    #pragma unroll
    for(int k=0;k<8;k++){
      int ri=r0+k;
      if(ri<R) tab[(size_t)ri*NCOLS+jn]=acc[k][u]*cs;
    }
  }
}

// shared table-role body
__device__ __forceinline__ void table_role(const float* __restrict__ W1, const float* __restrict__ W2,
    float* __restrict__ tab, int NCOLS, float scale, const float* __restrict__ PW,
    const int* __restrict__ NJ, int jb0, int jlim, int r0, int R, int NR,
    float (*__restrict__ sh_h)[8], int tid){
  {
    int c=tid;
    float wa=W1[c], wb=W1[256+c], wc=W1[512+c];
    const float A=(float)(1.14136*7.38905609893065*1.7320508075688772);
    #pragma unroll
    for(int k=0;k<8;k++){
      int ri=r0+k;
      float r=0.5f+2.0f*(float)ri/(float)NR;
      float sv[3];
      #pragma unroll
      for(int j=0;j<3;j++){
        float v=1.0f+0.5f*(float)j;
        float diff=(r-v)*2.0f;
        float u1=diff+1.0f, u2=1.0f-diff;
        float f1=(u1>0.0f)? expf(-1.0f/u1):0.0f;
        float f2=(u2>0.0f)? expf(-1.0f/u2):0.0f;
        sv[j]=A*f1*f2;
      }
      float hv=sv[0]*wa+sv[1]*wb+sv[2]*wc;
      hv=fmaxf(hv*0.5773502691896258f,0.0f)*(SQRT2F*0.0625f);
      sh_h[c][k]=hv;
    }
  }
  __syncthreads();
  int jb=jb0+tid*2;
  if(jb+2<=jlim)
    table_gemm2(W2,tab,NCOLS,scale,PW,NJ,jb,sh_h,r0,R);
}

// ---------------- front kernel A: TAB1 + tanh + edge geometry + Y1/Y2 zeroing ----------------
__global__ __launch_bounds__(256) void k_front_a(
    const float* __restrict__ W1_1, const float* __restrict__ W2_1, float* __restrict__ T1,
    const float* __restrict__ pos, const int* __restrict__ esrc, const int* __restrict__ edst,
    int R, int NR, int NXT, float* __restrict__ ws){
  __shared__ float sh_h[256][8];
  int bid=blockIdx.x;
  int tid=threadIdx.x;

  if(bid<NXT){
    table_role(W1_1,W2_1,T1,272,INV_SQRT_NEIGH,PWC1.v,CMETA1.newj,0,272,bid*8,R,NR,sh_h,tid);
    return;
  }
  bid-=NXT;

  if(bid==0){
    __shared__ double red[256];
    double loc=0.0;
    for(int i=tid;i<=100000;i+=256){
      float x=-8.0f+16.0f*(float)i/100000.0f;
      float th=tanhf(x);
      float pdf=expf(-0.5f*x*x)*0.3989422804014327f;
      loc += (double)(th*th*pdf);
    }
    red[tid]=loc; __syncthreads();
    for(int s=128;s>0;s>>=1){ if(tid<s) red[tid]+=red[tid+s]; __syncthreads(); }
    if(tid==0) ws[OFF_TANH]=(float)(1.0/sqrt(red[0]*(16.0/100000.0)));
    return;
  }
  bid-=1;

  if(bid<313){
    int e=bid*256+tid;
    if(e>=NEDGE) return;
    float* eattr=ws+OFF_EATTR;
    float* x0=ws+OFF_X0;
    int s=esrc[e], d=edst[e];
    float x=pos[3*s]-pos[3*d], y=pos[3*s+1]-pos[3*d+1], z=pos[3*s+2]-pos[3*d+2];
    float r=sqrtf(x*x+y*y+z*z+1e-12f);
    float iv=1.0f/r; x*=iv; y*=iv; z*=iv;
    const float s3=1.7320508075688772f, s5=2.2360679774997896f, s15=3.872983346207417f;
    const float s7=2.6457513110645907f, s42=6.48074069840786f, s70=8.366600265340756f, s105=10.246950765959598f;
    float Y[16];
    Y[0]=1.0f;
    Y[1]=s3*y; Y[2]=s3*z; Y[3]=s3*x;
    Y[4]=s15*x*y; Y[5]=s15*y*z; Y[6]=0.5f*s5*(3.0f*z*z-1.0f); Y[7]=s15*x*z; Y[8]=0.5f*s15*(x*x-y*y);
    Y[9]=0.25f*s70*y*(3.0f*x*x-y*y); Y[10]=s105*x*y*z; Y[11]=0.25f*s42*y*(5.0f*z*z-1.0f);
    Y[12]=0.5f*s7*z*(5.0f*z*z-3.0f); Y[13]=0.25f*s42*x*(5.0f*z*z-1.0f);
    Y[14]=0.5f*s105*z*(x*x-y*y); Y[15]=0.25f*s70*x*(x*x-3.0f*y*y);
    float4* ep=(float4*)(eattr+(size_t)e*16);
    ep[0]=make_float4(Y[0],Y[1],Y[2],Y[3]);
    ep[1]=make_float4(Y[4],Y[5],Y[6],Y[7]);
    ep[2]=make_float4(Y[8],Y[9],Y[10],Y[11]);
    ep[3]=make_float4(Y[12],Y[13],Y[14],Y[15]);
    #pragma unroll
    for(int i=0;i<16;i++)
      atomicAdd(&x0[(size_t)d*16+i], Y[i]*INV_SQRT_NEIGH);
    ws[OFF_RBUF+e]=r;
    if(r>0.5f && r<2.5f){
      float t=(r-0.5f)*((float)NR*0.5f);
      int i0=min((int)t, NR-1);
      atomicAdd((int*)(ws+OFF_HIST)+i0, 1);
    }
    return;
  }
  bid-=313;

  {
    float4* dst=(float4*)(ws+OFF_Y1);
    size_t n4=(size_t)(OFF_X1-OFF_Y1)/4;
    float4 z4=make_float4(0.f,0.f,0.f,0.f);
    for(size_t i=(size_t)bid*256+tid; i<n4; i+=(size_t)256*256)
      dst[i]=z4;
  }
}

// ---------------- exclusive scan of histogram -> offsets + total count ----------------
__global__ void k_scan(float* __restrict__ ws, int NR){
  __shared__ int sd[2048];
  int t=threadIdx.x;
  int* hist=(int*)(ws+OFF_HIST);
  int* offs=(int*)(ws+OFF_OFFS);
  int i1=t, i2=t+1024;
  sd[i1]=(i1<NR)? hist[i1]:0;
  sd[i2]=(i2<NR)? hist[i2]:0;
  __syncthreads();
  for(int d=1; d<2048; d<<=1){
    int v1=(i1>=d)? sd[i1-d]:0;
    int v2=(i2>=d)? sd[i2-d]:0;
    __syncthreads();
    sd[i1]+=v1; sd[i2]+=v2;
    __syncthreads();
  }
  if(i1<NR) offs[i1]=(i1==0)?0:sd[i1-1];
  if(i2<NR) offs[i2]=sd[i2-1];
  if(t==0){ offs[NR]=sd[NR-1]; *((int*)(ws+OFF_CNT))=sd[NR-1]; }
}

// ---------------- scatter active edges into r-sorted EINFO ----------------
__global__ void k_scatter(const int* __restrict__ esrc, const int* __restrict__ edst,
                          float* __restrict__ ws, int NR){
  int e=blockIdx.x*256+threadIdx.x;
  if(e>=NEDGE) return;
  float r=ws[OFF_RBUF+e];
  if(!(r>0.5f && r<2.5f)) return;
  float t=(r-0.5f)*((float)NR*0.5f);
  int i0=min((int)t, NR-1);
  int* offs=(int*)(ws+OFF_OFFS);
  int* cur=(int*)(ws+OFF_CUR);
  int p=offs[i0]+atomicAdd(&cur[i0],1);
  int4 v; v.x=esrc[e]; v.y=edst[e]; v.z=e; v.w=__float_as_int(t);
  ((int4*)(ws+OFF_EINFO))[p]=v;
}

// ---------------- conv1 + TAB2/TAB3 table blocks (overlapped) ----------------
__global__ __launch_bounds__(256,4) void k_conv1t(
    const float* __restrict__ W1_2, const float* __restrict__ W2_2, float* __restrict__ T2,
    const float* __restrict__ W1_3, const float* __restrict__ W2_3, float* __restrict__ T3,
    const float* __restrict__ xin, const float* __restrict__ TAB,
    float* __restrict__ yout, float* __restrict__ ws, int R, int NR, int NXT)
{
  __shared__ float sh_h[256][8];
  int bid=blockIdx.x;
  int tid=threadIdx.x;
  int NT2=7*NXT;

  if(bid<NT2+NXT){
    if(bid<NT2){
      int s=bid/NXT; int xt=bid-s*NXT; int jb0=s*512;
      int jlim=(jb0+512<3328)?(jb0+512):3328;
      table_role(W1_2,W2_2,T2,3328,INV_SQRT_NEIGH,PWC2.v,CMETA2.newj,jb0,jlim,xt*8,R,NR,sh_h,tid);
    } else {
      int xt=bid-NT2;
      table_role(W1_3,W2_3,T3,44,INV_SQRT_NEIGH*0.5f,PWC3.v,CMETA3.newj,0,44,xt*8,R,NR,sh_h,tid);
    }
    return;
  }
  bid-=NT2+NXT;

  // ---- conv1 role ----
  __shared__ float sh_a[8][20];
  __shared__ float sh_b[8][20];
  __shared__ float sh_core[8][33];
  __shared__ int sh_src[8], sh_dst[8], sh_eid[8];
  __shared__ float sh_t[8];

  int nact=*(const int*)(ws+OFF_CNT);
  int base=bid*8;
  if(base>=nact) return;
  int ne=min(8, nact-base);

  if(tid<8){
    int src=0,dst=0,eid=-1; float tv=0.0f;
    if(tid<ne){
      int4 v=((const int4*)(ws+OFF_EINFO))[base+tid];
      src=v.x; dst=v.y; eid=v.z; tv=__int_as_float(v.w);
    }
    sh_src[tid]=src; sh_dst[tid]=dst; sh_eid[tid]=eid; sh_t[tid]=tv;
  }
  __syncthreads();

  if(tid<32){
    int idx=tid>>2, c4=tid&3;
    int eid=sh_eid[idx];
    float4 v=make_float4(0.f,0.f,0.f,0.f);
    if(eid>=0) v=((const float4*)(ws+OFF_EATTR+(size_t)eid*16))[c4];
    *(float4*)&sh_b[idx][c4*4]=v;
  }
  if(tid>=32 && tid<64){
    int t2=tid-32; int idx=t2>>2, c4=t2&3;
    float4 v=make_float4(0.f,0.f,0.f,0.f);
    if(sh_eid[idx]>=0) v=((const float4*)(xin+(size_t)sh_src[idx]*16))[c4];
    *(float4*)&sh_a[idx][c4*4]=v;
  }
  __syncthreads();

  {
    constexpr int NIT=31;
    for(int z=tid; z<8*NIT; z+=256){
      int idx=z/NIT, rem=z-idx*NIT;
      CItem it=CIT1.it[rem];
      float acc=0.0f;
      for(int i=0;i<it.n1;i++){
        float av=sh_a[idx][it.aoff+i];
        int cb=it.cofs + i*it.n2*it.jstep;
        for(int j=0;j<it.n2;j++)
          acc += av*sh_b[idx][it.boff+j]*W3JC.v[cb + j*it.jstep];
      }
      sh_core[idx][it.woff]=acc;
    }
    __syncthreads();
  }

  {
    int e=tid&7;
    float tv=sh_t[e];
    int i0=min((int)tv, NR-1);
    float fr=tv-(float)i0;
    const float* T0=TAB+(size_t)i0*272;
    const float* crb=&sh_core[e][0];
    int dstv=sh_dst[e];
    bool act=(e<ne);

    for(int q=tid; q<8*96; q+=256){
      int c=q>>3;
      int s0=CMETA1.cidx[c], s1=CMETA1.cidx[c+1];
      int ob=CMETA1.obase[c], n3=CMETA1.n3c[c];
      int cnt=s1-s0;
      if(!cnt) continue;
      float a0=0.0f,a1=0.0f,a2=0.0f;
      const Ent2* ep=CMETA1.ent+s0;
      if(n3==1){
        switch(cnt){
          case 4: apply1_col<4,1,272>(ep,T0,crb,fr,a0,a1,a2); break;
          default: apply1_dyn(ep,cnt,1,T0,crb,fr,272,a0,a1,a2); break;
        }
      } else {
        switch(cnt){
          case 6: apply1_col<6,3,272>(ep,T0,crb,fr,a0,a1,a2); break;
          case 3: apply1_col<3,3,272>(ep,T0,crb,fr,a0,a1,a2); break;
          default: apply1_dyn(ep,cnt,3,T0,crb,fr,272,a0,a1,a2); break;
        }
      }
      if(act){
        float* yp=&yout[(size_t)dstv*160+ob];
        atomicAdd(yp, a0);
        if(n3==3){ atomicAdd(yp+1, a1); atomicAdd(yp+2, a2); }
      }
    }
  }
}

// ---------------- fused conv (conv2/conv3): gate + table-lerp + tensor product + scatter ----------------
template<int CONV,int DY,int D_IN,int D_OUT,int CSTRIDE,int NCOL,int NCOLS,bool FINAL>
__global__ __launch_bounds__(256,4) void k_conv(
    const float* __restrict__ xin, const float* __restrict__ TAB,
    float* __restrict__ yout, const int* __restrict__ batchp,
    float* __restrict__ ws, int NR)
{
  constexpr int APAD = D_IN+4;
  constexpr int NGP  = (CONV==2)?36:4;
  constexpr int YST  = (CONV==3)?132:4;
  constexpr int NGV  = (CONV==2)?32:((CONV==3)?24:1);
  __shared__ float sh_a[8][APAD];
  __shared__ float sh_b[8][20];
  __shared__ float sh_core[8][CSTRIDE];
  __shared__ float sh_g[8][NGP];
  __shared__ float sh_gv[8][NGV];
  __shared__ float sh_y[8][YST];
  __shared__ float sh_red[8];
  __shared__ int sh_src[8], sh_dst[8], sh_eid[8];
  __shared__ float sh_t[8];

  int tid=threadIdx.x;
  int nact=*(const int*)(ws+OFF_CNT);
  int base=blockIdx.x*8;
  if(base>=nact) return;
  int ne=min(8, nact-base);

  if(tid<8){
    int src=0,dst=0,eid=-1; float tv=0.0f;
    if(tid<ne){
      int4 v=((const int4*)(ws+OFF_EINFO))[base+tid];
      src=v.x; dst=v.y; eid=v.z; tv=__int_as_float(v.w);
    }
    sh_src[tid]=src; sh_dst[tid]=dst; sh_eid[tid]=eid; sh_t[tid]=tv;
    if constexpr(CONV==3) sh_red[tid]=0.0f;
  }
  __syncthreads();

  // stage b (8 x 16 floats) via float4
  if(tid<32){
    int idx=tid>>2, c4=tid&3;
    int eid=sh_eid[idx];
    float4 v=make_float4(0.f,0.f,0.f,0.f);
    if(eid>=0) v=((const float4*)(ws+OFF_EATTR+(size_t)eid*16))[c4];
    *(float4*)&sh_b[idx][c4*4]=v;
  }
  // stage raw y
  {
    constexpr int YQ=DY/4;
    for(int z=tid; z<8*YQ; z+=256){
      int idx=z/YQ, c4=z-idx*YQ;
      float4 v=make_float4(0.f,0.f,0.f,0.f);
      if(sh_eid[idx]>=0) v=((const float4*)(xin+(size_t)sh_src[idx]*DY))[c4];
      if constexpr(CONV==2) *(float4*)&sh_core[idx][c4*4]=v;   // park y in sh_core area
      else                  *(float4*)&sh_y[idx][c4*4]=v;
    }
  }
  __syncthreads();

  // ---- gate + core contraction ----
  {
    float TN=ws[OFF_TANH];
    for(int z=tid; z<8*NGV; z+=256){
      int idx=z/NGV, m=z-idx*NGV;
      const float* yr=(CONV==2)? &sh_core[idx][0] : &sh_y[idx][0];
      float u=yr[32+m];
      bool th=(CONV==2)? (((m>>3)&1)!=0) : (((m/6)&1)!=0);
      sh_gv[idx][m]= th? tanhf(u)*TN : fmaxf(u,0.0f)*SQRT2F;
    }
    constexpr int NG=(CONV==2)?34:4;
    for(int z=tid; z<8*NG; z+=256){
      int idx=z/NG, rem=z-idx*NG;
      GItem it=(CONV==2)? GIT2.it[rem] : GIT3.it[rem];
      float acc=0.0f;
      for(int j=0;j<it.n2;j++)
        acc += sh_b[idx][it.boff+j]*W3JC.v[it.cofs + j*it.jstep];
      sh_g[idx][rem]=acc;
    }
    __syncthreads();
    for(int z=tid; z<8*D_IN; z+=256){
      int idx=z/D_IN, o=z-idx*D_IN;
      const float* yr=(CONV==2)? &sh_core[idx][0] : &sh_y[idx][0];
      float val;
      if(o<16) val=fmaxf(yr[o],0.0f)*SQRT2F;
      else if(o<32) val=fabsf(yr[o]);
      else {
        if constexpr(CONV==2){
          int gi=(o<80)? (o-32)/3 : 16+(o-80)/3;
          val=yr[o+32]*sh_gv[idx][gi];
        } else {
          int gi=(o<68)? (o-32)/3 : 12+(o-68)/3;
          val=yr[o+24]*sh_gv[idx][gi];
        }
      }
      sh_a[idx][o]=val;
    }
    __syncthreads();
    constexpr int NO=(CONV==2)?448:44;
    for(int z=tid; z<8*NO; z+=256){
      int idx=z/NO, rem=z-idx*NO;
      OItem it=(CONV==2)? OIT2.it[rem] : OIT3.it[rem];
      float acc=0.0f;
      #pragma unroll 3
      for(int i=0;i<it.n1;i++)
        acc += sh_a[idx][it.aoff+i]*sh_g[idx][it.gofs + i*it.n3];
      sh_core[idx][it.woff]=acc;
    }
    __syncthreads();
  }

  // ---- apply ----
  if constexpr(CONV==3){
    if(tid<88){
      int e3=tid&7, c=tid>>3;
      float tv=sh_t[e3];
      int i0=min((int)tv, NR-1);
      float fr=tv-(float)i0;
      const float* tj=TAB+(size_t)i0*NCOLS + c*4;
      float4 w0=*(const float4*)tj;
      float4 w1=*(const float4*)(tj+NCOLS);
      float4 cv=*(const float4*)(&sh_core[e3][c*4]);
      float p;
      p  = (w0.x+fr*(w1.x-w0.x))*cv.x;
      p += (w0.y+fr*(w1.y-w0.y))*cv.y;
      p += (w0.z+fr*(w1.z-w0.z))*cv.z;
      p += (w0.w+fr*(w1.w-w0.w))*cv.w;
      atomicAdd(&sh_red[e3], p);
    }
    __syncthreads();
    if(tid<ne) atomicAdd(&ws[OFF_GSUM+batchp[sh_dst[tid]]], sh_red[tid]);
  } else {
    // ---- conv2 PAIR apply: thread = (edge-pair, column); shared-row loads ----
    for(int q=tid; q<4*NCOL; q+=256){
      int c=q>>2, p=q&3;
      int ea=2*p, eb=2*p+1;
      int s0=CMETA2.cidx[c], s1=CMETA2.cidx[c+1];
      int ob=CMETA2.obase[c], n3=CMETA2.n3c[c];
      int cnt=s1-s0;
      if(!cnt) continue;
      float tva=sh_t[ea], tvb=sh_t[eb];
      int ia=min((int)tva,NR-1), ib=min((int)tvb,NR-1);
      float fra=tva-(float)ia, frb=tvb-(float)ib;
      const float* Ta=TAB+(size_t)ia*NCOLS;
      const float* Tb=TAB+(size_t)ib*NCOLS;
      const float* cra=&sh_core[ea][0];
      const float* crbp=&sh_core[eb][0];
      bool srow=(ia==ib);
      float a0a=0.0f,a1a=0.0f,a2a=0.0f,a0b=0.0f,a1b=0.0f,a2b=0.0f;
      const Ent2* ep=CMETA2.ent+s0;
      if(n3==1){
        switch(cnt){
          case 3: apply2p_col<3,1,3328>(ep,Ta,Tb,cra,crbp,fra,frb,srow,a0a,a1a,a2a,a0b,a1b,a2b); break;
          case 1: apply2p_col<1,1,3328>(ep,Ta,Tb,cra,crbp,fra,frb,srow,a0a,a1a,a2a,a0b,a1b,a2b); break;
          default: apply2p_dyn(ep,cnt,1,Ta,Tb,cra,crbp,fra,frb,srow,3328,a0a,a1a,a2a,a0b,a1b,a2b); break;
        }
      } else {
        switch(cnt){
          case 5: apply2p_col<5,3,3328>(ep,Ta,Tb,cra,crbp,fra,frb,srow,a0a,a1a,a2a,a0b,a1b,a2b); break;
          case 3: apply2p_col<3,3,3328>(ep,Ta,Tb,cra,crbp,fra,frb,srow,a0a,a1a,a2a,a0b,a1b,a2b); break;
          default: apply2p_dyn(ep,cnt,3,Ta,Tb,cra,crbp,fra,frb,srow,3328,a0a,a1a,a2a,a0b,a1b,a2b); break;
        }
      }
      if(ea<ne){
        float* yp=&yout[(size_t)sh_dst[ea]*D_OUT+ob];
        atomicAdd(yp, a0a);
        if(n3==3){ atomicAdd(yp+1, a1a); atomicAdd(yp+2, a2a); }
      }
      if(eb<ne){
        float* yp=&yout[(size_t)sh_dst[eb]*D_OUT+ob];
        atomicAdd(yp, a0b);
        if(n3==3){ atomicAdd(yp+1, a1b); atomicAdd(yp+2, a2b); }
      }
    }
  }
}

__global__ void k_sig(const float* __restrict__ ws, float* __restrict__ out){
  int g=threadIdx.x;
  if(g<NGRAPH){
    float v=ws[OFF_GSUM+g];
    out[g]=1.0f/(1.0f+expf(-v));
  }
}

// ---------------- launch ----------------
extern "C" void kernel_launch(void* const* d_in, const int* in_sizes, int n_in,
                              void* d_out, int out_size, void* d_ws, size_t ws_size,
                              hipStream_t stream){
  const float* pos =(const float*)d_in[0];
  const float* w1_1=(const float*)d_in[1];
  const float* w2_1=(const float*)d_in[2];
  const float* w1_2=(const float*)d_in[3];
  const float* w2_2=(const float*)d_in[4];
  const float* w1_3=(const float*)d_in[5];
  const float* w2_3=(const float*)d_in[6];
  const int* esrc=(const int*)d_in[7];
  const int* edst=(const int*)d_in[8];
  const int* batch=(const int*)d_in[9];
  float* ws=(float*)d_ws;
  float* out=(float*)d_out;

  // table resolution adapted to available workspace (rows = NR+1)
  long availRows = ((long)(ws_size/4) - (long)OFF_TAB)/3644L;
  int R = (availRows < 1025L)? (int)availRows : 1025;
  if(R < 9) R = 9;
  int NR = R-1;
  int NXT = (R+7)/8;
  float* TAB1 = ws + OFF_TAB;
  float* TAB2 = TAB1 + (size_t)R*272;
  float* TAB3 = TAB2 + (size_t)R*3328;

  // zero: cnt/gsum, hist/offs/cur, x0 (needed BEFORE k_front_a's edge atomics)
  hipMemsetAsync(ws+OFF_CNT, 0, (size_t)(728-OFF_CNT)*sizeof(float), stream);
  hipMemsetAsync(ws+OFF_HIST, 0, (size_t)(13832-OFF_HIST)*sizeof(float), stream);
  hipMemsetAsync(ws+OFF_X0, 0, (size_t)(OFF_Y1-OFF_X0)*sizeof(float), stream);

  // front A: TAB1 + tanh + edge + zero(Y1,Y2)
  k_front_a<<<NXT+1+313+256,256,0,stream>>>(
      w1_1,w2_1,TAB1, pos, esrc, edst, R, NR, NXT, ws);
  k_scan<<<1,1024,0,stream>>>(ws, NR);
  k_scatter<<<(NEDGE+255)/256,256,0,stream>>>(esrc, edst, ws, NR);

  // conv1 overlapped with TAB2/TAB3 generation (needed only by conv2/conv3)
  k_conv1t<<<8*NXT+(NEDGE+7)/8,256,0,stream>>>(
      w1_2,w2_2,TAB2, w1_3,w2_3,TAB3,
      ws+OFF_X0, TAB1, ws+OFF_Y1, ws, R, NR, NXT);

  k_conv<2,160,128,128,452, 80,3328,false><<<(NEDGE+7)/8,256,0,stream>>>(
      ws+OFF_Y1, TAB2, ws+OFF_Y2, batch, ws, NR);

  k_conv<3,128,104,  1, 68,  1, 44,true ><<<(NEDGE+7)/8,256,0,stream>>>(
      ws+OFF_Y2, TAB3, nullptr, batch, ws, NR);

  k_sig<<<1,64,0,stream>>>(ws, out);
}

// Round 15
// 337.684 us; speedup vs baseline: 2.5149x; 2.5149x over previous
//
#include <hip/hip_runtime.h>
#include <math.h>

#define NNODE 20000
#define NEDGE 80000
#define NGRAPH 64

// ---------------- workspace layout (float offsets) ----------------
#define OFF_TANH  656
#define OFF_CNT   660
#define OFF_GSUM  664
#define OFF_HIST  7680
#define OFF_OFFS  9728
#define OFF_CUR   11784
#define OFF_EATTR 14336
#define OFF_RBUF  1294336
#define OFF_EINFO 1374336
#define OFF_X0    1694336
#define OFF_Y1    2014336
#define OFF_Y2    5214336
#define OFF_X1    7774336
#define OFF_X2    10334336
#define OFF_TAB   12414336

// w3j table offsets
#define T000 0
#define T110 1
#define T220 10
#define T330 35
#define T011 84
#define T101 93
#define T111 102
#define T121 129
#define T211 174
#define T231 219
#define T321 324
#define T221 429
#define T331 504

#define INV_SQRT_NEIGH 0.5129891760425771f
#define SQRT2F 1.4142135623730951f

struct TabD { int l1,l2,l3,off; };
constexpr TabD HTABS[13] = {
  {0,0,0,T000},{1,1,0,T110},{2,2,0,T220},{3,3,0,T330},
  {0,1,1,T011},{1,0,1,T101},{1,1,1,T111},{1,2,1,T121},
  {2,1,1,T211},{2,3,1,T231},{3,2,1,T321},{2,2,1,T221},{3,3,1,T331}
};

struct CoreD { short a_off, b_off; short l1,l2,l3; short tab; short coff; short m1; };
struct PathD { short core; short wofs, wend, ooff; short mo, lo; float pw; };

// ---- conv1: SH (x) SH -> GATE1_IN ----
constexpr CoreD HCORES1[13] = {
  {0,0, 0,0,0, T000, 0, 1},
  {0,1, 0,1,1, T011, 1, 1},
  {1,0, 1,0,1, T101, 4, 1},
  {1,1, 1,1,0, T110, 7, 1},
  {1,1, 1,1,1, T111, 8, 1},
  {1,4, 1,2,1, T121, 11, 1},
  {4,1, 2,1,1, T211, 14, 1},
  {4,4, 2,2,0, T220, 17, 1},
  {4,4, 2,2,1, T221, 18, 1},
  {4,9, 2,3,1, T231, 21, 1},
  {9,4, 3,2,1, T321, 24, 1},
  {9,9, 3,3,0, T330, 27, 1},
  {9,9, 3,3,1, T331, 28, 1}
};
#define PWR 0.7071067811865476f
constexpr PathD HPATHS1[21] = {
  {0,  0, 16,  0,16,0,0.5f},
  {0, 16, 24, 32, 8,0,0.5f},
  {0, 24, 32, 48, 8,0,0.5f},
  {1, 32, 48, 64,16,1,PWR},
  {2, 48, 64, 64,16,1,PWR},
  {3, 64, 80,  0,16,0,0.5f},
  {3, 80, 88, 32, 8,0,0.5f},
  {3, 88, 96, 48, 8,0,0.5f},
  {4, 96,112,112,16,1,1.0f},
  {5,112,128, 64,16,1,PWR},
  {6,128,144, 64,16,1,PWR},
  {7,144,160,  0,16,0,0.5f},
  {7,160,168, 32, 8,0,0.5f},
  {7,168,176, 48, 8,0,0.5f},
  {8,176,192,112,16,1,1.0f},
  {9,192,208, 64,16,1,PWR},
  {10,208,224,64,16,1,PWR},
  {11,224,240, 0,16,0,0.5f},
  {11,240,248,32, 8,0,0.5f},
  {11,248,256,48, 8,0,0.5f},
  {12,256,272,112,16,1,1.0f}
};

// ---- conv2: GATE1_OUT (x) SH -> GATE2_IN ----
constexpr CoreD HCORES2[12] = {
  {0,0,  0,0,0, T000, 0,   16},
  {0,1,  0,1,1, T011, 16,  16},
  {16,0, 0,0,0, T000, 64,  16},
  {16,1, 0,1,1, T011, 80,  16},
  {32,0, 1,0,1, T101, 128, 16},
  {32,1, 1,1,0, T110, 176, 16},
  {32,1, 1,1,1, T111, 192, 16},
  {32,4, 1,2,1, T121, 240, 16},
  {80,0, 1,0,1, T101, 288, 16},
  {80,1, 1,1,0, T110, 336, 16},
  {80,1, 1,1,1, T111, 352, 16},
  {80,4, 1,2,1, T121, 400, 16}
};
#define PA 0.14433756729740643f
#define PB 0.25f
#define PC 0.19364916731037085f
constexpr PathD HPATHS2[20] = {
  {0,   0, 256,  0,16,0,PA},
  {0, 256, 352, 32, 6,0,PA},
  {0, 352, 448, 44, 6,0,PA},
  {1, 448, 640, 56,12,1,PC},
  {2, 640, 896,  0,16,0,PA},
  {2, 896, 992, 32, 6,0,PA},
  {2, 992,1088, 44, 6,0,PA},
  {3,1088,1280, 56,12,1,PC},
  {4,1280,1472, 56,12,1,PC},
  {5,1472,1728,  0,16,0,PA},
  {5,1728,1824, 32, 6,0,PA},
  {5,1824,1920, 44, 6,0,PA},
  {6,1920,2112, 92,12,1,PB},
  {7,2112,2304, 56,12,1,PC},
  {8,2304,2496, 92,12,1,PB},
  {9,2496,2752, 16,16,0,PB},
  {9,2752,2848, 38, 6,0,PB},
  {9,2848,2944, 50, 6,0,PB},
  {10,2944,3136,56,12,1,PC},
  {11,3136,3328,92,12,1,PB}
};

// ---- conv3: GATE2_OUT (x) SH -> OUT_FINAL ----
constexpr CoreD HCORES3[3] = {
  {0,0,  0,0,0, T000, 0,  16},
  {16,0, 0,0,0, T000, 16, 16},
  {32,1, 1,1,0, T110, 32, 12}
};
#define PD 0.15075567228888181f
constexpr PathD HPATHS3[3] = {
  {0, 0,16, 0,1,0,PD},
  {1,16,32, 0,1,0,PD},
  {2,32,44, 0,1,0,PD}
};

// ================= compile-time w3j tables (exact port of reference) =================
constexpr double FACT[9] = {1.0,1.0,2.0,6.0,24.0,120.0,720.0,5040.0,40320.0};

constexpr double csqrt_(double x){
  if(x<=0.0) return 0.0;
  double g = (x<1.0)? 1.0 : x;
  for(int i=0;i<40;i++) g = 0.5*(g + x/g);
  return g;
}

constexpr double cw3j_(int j1,int j2,int j3,int m1,int m2,int m3){
  if(m1+m2+m3!=0) return 0.0;
  int t1=j2-m1-j3, t2=j1+m2-j3, t3=j1+j2-j3, t4=j1-m1, t5=j2+m2;
  int tmin=t1>0?t1:0; if(t2>tmin) tmin=t2;
  int tmax=t3<t4?t3:t4; if(t5<tmax) tmax=t5;
  if(tmin>tmax) return 0.0;
  double s=0.0;
  for(int t=tmin;t<=tmax;++t){
    double d=FACT[t]*FACT[t-t1]*FACT[t-t2]*FACT[t3-t]*FACT[t4-t]*FACT[t5-t];
    s += ((t&1)? -1.0:1.0)/d;
  }
  double tri=FACT[j1+j2-j3]*FACT[j1-j2+j3]*FACT[-j1+j2+j3]/FACT[j1+j2+j3+1];
  double nrm=csqrt_(tri*FACT[j1+m1]*FACT[j1-m1]*FACT[j2+m2]*FACT[j2-m2]*FACT[j3+m3]*FACT[j3-m3]);
  return (((j1-j2-m3)&1)? -1.0:1.0)*nrm*s;
}

constexpr int curow_(int l,int i,int* a,double* re,double* im){
  const double is2=0.7071067811865475;
  int m=i-l;
  if(m==0){ a[0]=l; re[0]=1.0; im[0]=0.0; return 1; }
  if(m>0){
    a[0]=l+m; re[0]=((m&1)? -is2:is2); im[0]=0.0;
    a[1]=l-m; re[1]=is2; im[1]=0.0; return 2;
  }
  int mm=-m;
  a[0]=l-mm; re[0]=0.0; im[0]=is2;
  a[1]=l+mm; re[1]=0.0; im[1]=((mm&1)? is2:-is2);
  return 2;
}

constexpr float cw3j_elem_(int l1,int l2,int l3,int i,int j,int k){
  int aa[2]={0,0},bb[2]={0,0},cc[2]={0,0};
  double ar[2]={0,0},ai[2]={0,0},br[2]={0,0},bi[2]={0,0},cr[2]={0,0},ci[2]={0,0};
  int na=curow_(l1,i,aa,ar,ai);
  int nb=curow_(l2,j,bb,br,bi);
  int nc=curow_(l3,k,cc,cr,ci);
  double accr=0.0, acci=0.0;
  for(int x=0;x<na;x++)for(int y=0;y<nb;y++)for(int w=0;w<nc;w++){
    double wv=cw3j_(l1,l2,l3, aa[x]-l1, bb[y]-l2, cc[w]-l3);
    if(wv==0.0) continue;
    double pr=ar[x]*br[y]-ai[x]*bi[y];
    double pi=ar[x]*bi[y]+ai[x]*br[y];
    double qr=pr*cr[w]-pi*ci[w];
    double qi=pr*ci[w]+pi*cr[w];
    accr+=qr*wv; acci+=qi*wv;
  }
  int Lm=(l1+l2+l3)&3;  // Re((-i)^L * acc)
  double res = (Lm==0)? accr : (Lm==1)? acci : (Lm==2)? -accr : -acci;
  return (float)res;
}

struct WApart { float v[429]; };
constexpr WApart gen_wa_(){
  WApart o{};
  for(int t=0;t<11;t++){
    int l1=HTABS[t].l1,l2=HTABS[t].l2,l3=HTABS[t].l3;
    int n2=2*l2+1,n3=2*l3+1;
    int tot=(2*l1+1)*n2*n3;
    for(int z=0;z<tot;z++){
      int i=z/(n2*n3), j=(z/n3)%n2, k=z%n3;
      o.v[HTABS[t].off+z]=cw3j_elem_(l1,l2,l3,i,j,k);
    }
  }
  return o;
}
struct WBpart { float v[222]; };
constexpr WBpart gen_wb_(){
  WBpart o{};
  for(int t=11;t<13;t++){
    int l1=HTABS[t].l1,l2=HTABS[t].l2,l3=HTABS[t].l3;
    int n2=2*l2+1,n3=2*l3+1;
    int tot=(2*l1+1)*n2*n3;
    for(int z=0;z<tot;z++){
      int i=z/(n2*n3), j=(z/n3)%n2, k=z%n3;
      o.v[HTABS[t].off-429+z]=cw3j_elem_(l1,l2,l3,i,j,k);
    }
  }
  return o;
}
constexpr WApart WAC = gen_wa_();
constexpr WBpart WBC = gen_wb_();
struct W3Full { float v[651]; };
constexpr W3Full gen_wfull_(){
  W3Full f{};
  for(int i=0;i<429;i++) f.v[i]=WAC.v[i];
  for(int i=0;i<222;i++) f.v[429+i]=WBC.v[i];
  return f;
}
__constant__ W3Full W3JC = gen_wfull_();

// ================= compile-time per-j path-weight scale =================
template<int NW> struct PwArr { float v[NW]; };
template<int NW,int NP>
constexpr PwArr<NW> gen_pw_(const PathD (&P)[NP]){
  PwArr<NW> a{};
  for(int p=0;p<NP;p++)
    for(int j=P[p].wofs;j<P[p].wend;j++) a.v[j]=P[p].pw;
  return a;
}
__constant__ PwArr<272>  PWC1 = gen_pw_<272>(HPATHS1);
__constant__ PwArr<3328> PWC2 = gen_pw_<3328>(HPATHS2);
__constant__ PwArr<44>   PWC3 = gen_pw_<44>(HPATHS3);

// ================= compile-time column-based apply metadata + table permutation =================
struct OutSeg { int mult, l; };
constexpr OutSeg OSEG1[8] = {{16,0},{16,0},{8,0},{8,0},{8,0},{8,0},{16,1},{16,1}};
constexpr OutSeg OSEG2[8] = {{16,0},{16,0},{6,0},{6,0},{6,0},{6,0},{12,1},{12,1}};
constexpr OutSeg OSEG3[1] = {{1,0}};

struct Ent2 { int jb, cb, nu; };  // weights at T[jb .. jb+nu) (new layout); core block cb (u-major)
template<int NCOL,int NENT,int NW> struct ColMetaT {
  int cidx[NCOL+1];
  int obase[NCOL];
  int n3c[NCOL];
  Ent2 ent[NENT];
  int newj[NW];     // old j -> new j (used by table writer)
};

template<int NCOL,int NENT,int NW,int NSEG,int NP,int NC>
constexpr ColMetaT<NCOL,NENT,NW> gen_colmeta_(const OutSeg (&S)[NSEG], const PathD (&P)[NP], const CoreD (&C)[NC]){
  ColMetaT<NCOL,NENT,NW> m{};
  int col=0, cnt=0, o=0, nb=0;
  for(int s=0;s<NSEG;s++){
    int n3=2*S[s].l+1;
    for(int wc=0;wc<S[s].mult;wc++){
      m.cidx[col]=cnt;
      int ob=o+wc*n3;
      m.obase[col]=ob;
      m.n3c[col]=n3;
      for(int p=0;p<NP;p++){
        PathD pd=P[p];
        int pn3=2*pd.lo+1;
        if(pn3!=n3) continue;
        int rel=ob-pd.ooff;
        if(rel<0||rel>=pd.mo*pn3) continue;
        int w=rel/pn3;
        CoreD cd=C[pd.core];
        int m1=cd.m1;
        m.ent[cnt]=Ent2{nb,(int)cd.coff,m1};
        for(int u=0;u<m1;u++) m.newj[pd.wofs + w + u*pd.mo]=nb+u;
        nb+=m1;
        cnt++;
      }
      col++;
    }
    o+=S[s].mult*n3;
  }
  m.cidx[col]=cnt;
  return m;
}

__constant__ ColMetaT<96,272,272>  CMETA1 = gen_colmeta_<96,272,272>(OSEG1, HPATHS1, HCORES1);
__constant__ ColMetaT<80,208,3328> CMETA2 = gen_colmeta_<80,208,3328>(OSEG2, HPATHS2, HCORES2);
__constant__ ColMetaT< 1,  3,  44> CMETA3 = gen_colmeta_< 1,  3,  44>(OSEG3, HPATHS3, HCORES3);

// ================= core-contraction metadata =================
struct CItem { short aoff, boff, n1, n2, cofs, jstep, woff, pad; };
struct CArr1 { CItem it[31]; };
constexpr CArr1 gen_c1_(){
  CArr1 a{}; int s=0;
  for(int cn=0;cn<13;cn++){
    CoreD cd=HCORES1[cn];
    int n1=2*cd.l1+1,n2=2*cd.l2+1,n3=2*cd.l3+1;
    for(int k=0;k<n3;k++){
      a.it[s]=CItem{cd.a_off,cd.b_off,(short)n1,(short)n2,(short)(cd.tab+k),(short)n3,(short)(cd.coff+k),0};
      s++;
    }
  }
  return a;
}
__constant__ CArr1 CIT1 = gen_c1_();

struct Fam { short b_off, tab, n1, n2, n3, goff; };
constexpr Fam GF2[6]={
  {0,T000,1,1,1,0},{1,T011,1,3,3,1},{0,T101,3,1,3,4},
  {1,T110,3,3,1,13},{1,T111,3,3,3,16},{4,T121,3,5,3,25}};
constexpr Fam GF3[2]={{0,T000,1,1,1,0},{1,T110,3,3,1,1}};
struct CoreG { short fam,a_off,m1,coff; };
constexpr CoreG CG2[12]={
  {0,0,16,0},{1,0,16,16},{0,16,16,64},{1,16,16,80},
  {2,32,16,128},{3,32,16,176},{4,32,16,192},{5,32,16,240},
  {2,80,16,288},{3,80,16,336},{4,80,16,352},{5,80,16,400}};
constexpr CoreG CG3[3]={{0,0,16,0},{0,16,16,16},{1,32,12,32}};

struct GItem { short boff, cofs, n2, jstep; };
template<int NG> struct GArrT { GItem it[NG]; };
template<int NG,int NF>
constexpr GArrT<NG> gen_g_(const Fam (&F)[NF]){
  GArrT<NG> a{}; int s=0;
  for(int f=0;f<NF;f++){
    for(int i=0;i<F[f].n1;i++)for(int k=0;k<F[f].n3;k++){
      a.it[s]=GItem{F[f].b_off,(short)(F[f].tab + i*F[f].n2*F[f].n3 + k),F[f].n2,F[f].n3};
      s++;
    }
  }
  return a;
}
__constant__ GArrT<34> GIT2=gen_g_<34>(GF2);
__constant__ GArrT<4>  GIT3=gen_g_<4>(GF3);

struct OItem { short aoff, gofs, n1, n3, woff, pad; };
template<int NO> struct OArrT { OItem it[NO]; };
template<int NO,int NC,int NF>
constexpr OArrT<NO> gen_o_(const CoreG (&C)[NC], const Fam (&F)[NF]){
  OArrT<NO> a{}; int s=0;
  for(int cn=0;cn<NC;cn++){
    Fam f=F[C[cn].fam];
    for(int k=0;k<f.n3;k++)for(int u=0;u<C[cn].m1;u++){
      a.it[s]=OItem{(short)(C[cn].a_off+u*f.n1),(short)(f.goff+k),f.n1,f.n3,
                    (short)(C[cn].coff+k*C[cn].m1+u),0};
      s++;
    }
  }
  return a;
}
__constant__ OArrT<448> OIT2=gen_o_<448,12,6>(CG2,GF2);
__constant__ OArrT<44>  OIT3=gen_o_<44,3,2>(CG3,GF3);

// ---------------- unrolled apply column processors ----------------
// conv1: nu==1 entries, weights contiguous at ep[0].jb
template<int CNT,int N3,int NCOLS>
__device__ __forceinline__ void apply1_col(const Ent2* __restrict__ ep, const float* __restrict__ T0,
    const float* __restrict__ crb, float fr, float&a0,float&a1,float&a2){
  const float* tja=T0+ep[0].jb;
  float wv[CNT];
  #pragma unroll
  for(int t=0;t<CNT;t++){
    float w0=tja[t], w1=tja[t+NCOLS];
    wv[t]=w0+fr*(w1-w0);
  }
  #pragma unroll
  for(int t=0;t<CNT;t++){
    const float* cr=crb+ep[t].cb;
    a0=fmaf(wv[t],cr[0],a0);
    if constexpr(N3==3){ a1=fmaf(wv[t],cr[1],a1); a2=fmaf(wv[t],cr[2],a2); }
  }
}
__device__ __forceinline__ void apply1_dyn(const Ent2* __restrict__ ep, int cnt, int n3,
    const float* __restrict__ T0, const float* __restrict__ crb, float fr, int NCOLS,
    float&a0,float&a1,float&a2){
  const float* tja=T0+ep[0].jb;
  for(int t=0;t<cnt;t++){
    float w0=tja[t], w1=tja[t+NCOLS];
    float w=w0+fr*(w1-w0);
    const float* cr=crb+ep[t].cb;
    a0=fmaf(w,cr[0],a0);
    if(n3==3){ a1=fmaf(w,cr[1],a1); a2=fmaf(w,cr[2],a2); }
  }
}
// conv2: nu==16 entries (single-accumulator form)
template<int CNT,int N3,int NCOLS>
__device__ __forceinline__ void apply2_col(const Ent2* __restrict__ ep, const float* __restrict__ T0,
    const float* __restrict__ crb, float fr, float&a0,float&a1,float&a2){
  #pragma unroll
  for(int t=0;t<CNT;t++){
    const float* cr=crb+ep[t].cb;
    const float* tj=T0+ep[t].jb;
    #pragma unroll
    for(int uu=0;uu<16;uu+=4){
      float4 w0=*(const float4*)(tj+uu);
      float4 w1=*(const float4*)(tj+NCOLS+uu);
      float w;
      if constexpr(N3==1){
        float4 cv=*(const float4*)(cr+uu);
        w=w0.x+fr*(w1.x-w0.x); a0=fmaf(w,cv.x,a0);
        w=w0.y+fr*(w1.y-w0.y); a0=fmaf(w,cv.y,a0);
        w=w0.z+fr*(w1.z-w0.z); a0=fmaf(w,cv.z,a0);
        w=w0.w+fr*(w1.w-w0.w); a0=fmaf(w,cv.w,a0);
      } else {
        float4 c0=*(const float4*)(cr+uu);
        float4 c1=*(const float4*)(cr+16+uu);
        float4 c2=*(const float4*)(cr+32+uu);
        w=w0.x+fr*(w1.x-w0.x); a0=fmaf(w,c0.x,a0); a1=fmaf(w,c1.x,a1); a2=fmaf(w,c2.x,a2);
        w=w0.y+fr*(w1.y-w0.y); a0=fmaf(w,c0.y,a0); a1=fmaf(w,c1.y,a1); a2=fmaf(w,c2.y,a2);
        w=w0.z+fr*(w1.z-w0.z); a0=fmaf(w,c0.z,a0); a1=fmaf(w,c1.z,a1); a2=fmaf(w,c2.z,a2);
        w=w0.w+fr*(w1.w-w0.w); a0=fmaf(w,c0.w,a0); a1=fmaf(w,c1.w,a1); a2=fmaf(w,c2.w,a2);
      }
    }
  }
}
__device__ __forceinline__ void apply2_dyn(const Ent2* __restrict__ ep, int cnt, int n3,
    const float* __restrict__ T0, const float* __restrict__ crb, float fr, int NCOLS,
    float&a0,float&a1,float&a2){
  for(int t=0;t<cnt;t++){
    const float* cr=crb+ep[t].cb;
    const float* tj=T0+ep[t].jb;
    #pragma unroll
    for(int uu=0;uu<16;uu+=4){
      float4 w0=*(const float4*)(tj+uu);
      float4 w1=*(const float4*)(tj+NCOLS+uu);
      float w;
      if(n3==1){
        float4 cv=*(const float4*)(cr+uu);
        w=w0.x+fr*(w1.x-w0.x); a0=fmaf(w,cv.x,a0);
        w=w0.y+fr*(w1.y-w0.y); a0=fmaf(w,cv.y,a0);
        w=w0.z+fr*(w1.z-w0.z); a0=fmaf(w,cv.z,a0);
        w=w0.w+fr*(w1.w-w0.w); a0=fmaf(w,cv.w,a0);
      } else {
        float4 c0=*(const float4*)(cr+uu);
        float4 c1=*(const float4*)(cr+16+uu);
        float4 c2=*(const float4*)(cr+32+uu);
        w=w0.x+fr*(w1.x-w0.x); a0=fmaf(w,c0.x,a0); a1=fmaf(w,c1.x,a1); a2=fmaf(w,c2.x,a2);
        w=w0.y+fr*(w1.y-w0.y); a0=fmaf(w,c0.y,a0); a1=fmaf(w,c1.y,a1); a2=fmaf(w,c2.y,a2);
        w=w0.z+fr*(w1.z-w0.z); a0=fmaf(w,c0.z,a0); a1=fmaf(w,c1.z,a1); a2=fmaf(w,c2.z,a2);
        w=w0.w+fr*(w1.w-w0.w); a0=fmaf(w,c0.w,a0); a1=fmaf(w,c1.w,a1); a2=fmaf(w,c2.w,a2);
      }
    }
  }
}

// ---------------- register-tiled table GEMM with depth-1 W2 prefetch ----------------
template<int JT>
__device__ __forceinline__ void ldw_(float* w, const float* p){
  if constexpr(JT==2) *(float2*)w = *(const float2*)p;
  else if constexpr(JT==4) *(float4*)w = *(const float4*)p;
  else { *(float4*)w=*(const float4*)p; *(float4*)(w+4)=*(const float4*)(p+4); }
}
template<int JT>
__device__ __forceinline__ void table_gemm(const float* __restrict__ W2, float* __restrict__ tab,
    int NCOLS, float scale, const float* __restrict__ PW, const int* __restrict__ NJ,
    int jb, const float (*__restrict__ sh_h)[8], int r0, int R){
  float acc[8][JT];
  #pragma unroll
  for(int k=0;k<8;k++)
    #pragma unroll
    for(int u=0;u<JT;u++) acc[k][u]=0.0f;
  const float* w2p=W2+jb;
  float w0[JT], w1[JT];
  ldw_<JT>(w0, w2p);
  ldw_<JT>(w1, w2p+NCOLS);
  for(int c=0;c<256;c+=2){
    int cp0=(c+2<256)?(c+2):255;
    int cp1=(c+3<256)?(c+3):255;
    float n0[JT], n1[JT];
    ldw_<JT>(n0, w2p+(size_t)cp0*NCOLS);
    ldw_<JT>(n1, w2p+(size_t)cp1*NCOLS);
    float h0[8], h1[8];
    *(float4*)&h0[0]=*(const float4*)&sh_h[c][0];
    *(float4*)&h0[4]=*(const float4*)&sh_h[c][4];
    *(float4*)&h1[0]=*(const float4*)&sh_h[c+1][0];
    *(float4*)&h1[4]=*(const float4*)&sh_h[c+1][4];
    #pragma unroll
    for(int k=0;k<8;k++)
      #pragma unroll
      for(int u=0;u<JT;u++)
        acc[k][u]=fmaf(h0[k],w0[u],acc[k][u]);
    #pragma unroll
    for(int k=0;k<8;k++)
      #pragma unroll
      for(int u=0;u<JT;u++)
        acc[k][u]=fmaf(h1[k],w1[u],acc[k][u]);
    #pragma unroll
    for(int u=0;u<JT;u++){ w0[u]=n0[u]; w1[u]=n1[u]; }
  }
  #pragma unroll
  for(int u=0;u<JT;u++){
    float cs=scale*PW[jb+u];
    int jn=NJ[jb+u];
    #pragma unroll
    for(int k=0;k<8;k++){
      int ri=r0+k;
      if(ri<R) tab[(size_t)ri*NCOLS+jn]=acc[k][u]*cs;
    }
  }
}

// ---------------- fused front kernel ----------------
// 1-D grid, block roles by blockIdx range (tables first = critical path):
//   [0, 7*NXT)            conv2 table slices (512 old-j cols each)
//   [7*NXT, 8*NXT)        conv1 table
//   [8*NXT, 9*NXT)        conv3 table
//   [9*NXT]               tanh
//   [.. +313)             edge geometry (SH, x0 scatter, r, histogram)
//   [.. +256)             zero Y1+Y2 accumulators (consumed by conv1/conv2 later)
__global__ __launch_bounds__(256) void k_front(
    const float* __restrict__ W1_1, const float* __restrict__ W2_1, float* __restrict__ T1,
    const float* __restrict__ W1_2, const float* __restrict__ W2_2, float* __restrict__ T2,
    const float* __restrict__ W1_3, const float* __restrict__ W2_3, float* __restrict__ T3,
    const float* __restrict__ pos, const int* __restrict__ esrc, const int* __restrict__ edst,
    int R, int NR, int NXT, float* __restrict__ ws){
  __shared__ float sh_h[256][8];
  int bid=blockIdx.x;
  int tid=threadIdx.x;
  int NT2=7*NXT;

  if(bid<NT2+2*NXT){
    // ---- table role ----
    int jb0, jlim, xt;
    const float* W1; const float* W2; float* tab; int NCOLS; float scale;
    const float* PW; const int* NJ;
    if(bid<NT2){
      int s=bid/NXT; xt=bid-s*NXT; jb0=s*512; jlim=(jb0+512<3328)?(jb0+512):3328;
      W1=W1_2; W2=W2_2; tab=T2; NCOLS=3328; scale=INV_SQRT_NEIGH; PW=PWC2.v; NJ=CMETA2.newj;
    } else if(bid<NT2+NXT){
      xt=bid-NT2; jb0=0; jlim=272;
      W1=W1_1; W2=W2_1; tab=T1; NCOLS=272; scale=INV_SQRT_NEIGH; PW=PWC1.v; NJ=CMETA1.newj;
    } else {
      xt=bid-NT2-NXT; jb0=0; jlim=44;
      W1=W1_3; W2=W2_3; tab=T3; NCOLS=44; scale=INV_SQRT_NEIGH*0.5f; PW=PWC3.v; NJ=CMETA3.newj;
    }
    int r0=xt*8;
    {
      int c=tid;
      float wa=W1[c], wb=W1[256+c], wc=W1[512+c];
      const float A=(float)(1.14136*7.38905609893065*1.7320508075688772);
      #pragma unroll
      for(int k=0;k<8;k++){
        int ri=r0+k;
        float r=0.5f+2.0f*(float)ri/(float)NR;
        float sv[3];
        #pragma unroll
        for(int j=0;j<3;j++){
          float v=1.0f+0.5f*(float)j;
          float diff=(r-v)*2.0f;
          float u1=diff+1.0f, u2=1.0f-diff;
          float f1=(u1>0.0f)? expf(-1.0f/u1):0.0f;
          float f2=(u2>0.0f)? expf(-1.0f/u2):0.0f;
          sv[j]=A*f1*f2;
        }
        float hv=sv[0]*wa+sv[1]*wb+sv[2]*wc;
        hv=fmaxf(hv*0.5773502691896258f,0.0f)*(SQRT2F*0.0625f);
        sh_h[c][k]=hv;
      }
    }
    __syncthreads();
    int jb=jb0+tid*2;
    if(jb+2<=jlim)
      table_gemm<2>(W2,tab,NCOLS,scale,PW,NJ,jb,sh_h,r0,R);
    return;
  }
  bid-=NT2+2*NXT;

  if(bid==0){
    // ---- TANH_NORM (matches reference Riemann sum) ----
    __shared__ double red[256];
    double loc=0.0;
    for(int i=tid;i<=100000;i+=256){
      float x=-8.0f+16.0f*(float)i/100000.0f;
      float th=tanhf(x);
      float pdf=expf(-0.5f*x*x)*0.3989422804014327f;
      loc += (double)(th*th*pdf);
    }
    red[tid]=loc; __syncthreads();
    for(int s=128;s>0;s>>=1){ if(tid<s) red[tid]+=red[tid+s]; __syncthreads(); }
    if(tid==0) ws[OFF_TANH]=(float)(1.0/sqrt(red[0]*(16.0/100000.0)));
    return;
  }
  bid-=1;

  if(bid<313){
    // ---- edge geometry role ----
    int e=bid*256+tid;
    if(e>=NEDGE) return;
    float* eattr=ws+OFF_EATTR;
    float* x0=ws+OFF_X0;
    int s=esrc[e], d=edst[e];
    float x=pos[3*s]-pos[3*d], y=pos[3*s+1]-pos[3*d+1], z=pos[3*s+2]-pos[3*d+2];
    float r=sqrtf(x*x+y*y+z*z+1e-12f);
    float iv=1.0f/r; x*=iv; y*=iv; z*=iv;
    const float s3=1.7320508075688772f, s5=2.2360679774997896f, s15=3.872983346207417f;
    const float s7=2.6457513110645907f, s42=6.48074069840786f, s70=8.366600265340756f, s105=10.246950765959598f;
    float Y[16];
    Y[0]=1.0f;
    Y[1]=s3*y; Y[2]=s3*z; Y[3]=s3*x;
    Y[4]=s15*x*y; Y[5]=s15*y*z; Y[6]=0.5f*s5*(3.0f*z*z-1.0f); Y[7]=s15*x*z; Y[8]=0.5f*s15*(x*x-y*y);
    Y[9]=0.25f*s70*y*(3.0f*x*x-y*y); Y[10]=s105*x*y*z; Y[11]=0.25f*s42*y*(5.0f*z*z-1.0f);
    Y[12]=0.5f*s7*z*(5.0f*z*z-3.0f); Y[13]=0.25f*s42*x*(5.0f*z*z-1.0f);
    Y[14]=0.5f*s105*z*(x*x-y*y); Y[15]=0.25f*s70*x*(x*x-3.0f*y*y);
    float4* ep=(float4*)(eattr+(size_t)e*16);
    ep[0]=make_float4(Y[0],Y[1],Y[2],Y[3]);
    ep[1]=make_float4(Y[4],Y[5],Y[6],Y[7]);
    ep[2]=make_float4(Y[8],Y[9],Y[10],Y[11]);
    ep[3]=make_float4(Y[12],Y[13],Y[14],Y[15]);
    #pragma unroll
    for(int i=0;i<16;i++)
      atomicAdd(&x0[(size_t)d*16+i], Y[i]*INV_SQRT_NEIGH);
    ws[OFF_RBUF+e]=r;
    if(r>0.5f && r<2.5f){
      float t=(r-0.5f)*((float)NR*0.5f);
      int i0=min((int)t, NR-1);
      atomicAdd((int*)(ws+OFF_HIST)+i0, 1);
    }
    return;
  }
  bid-=313;

  // ---- zero Y1+Y2 role (float4 grid-stride) ----
  {
    float4* dst=(float4*)(ws+OFF_Y1);
    size_t n4=(size_t)(OFF_X1-OFF_Y1)/4;
    float4 z4=make_float4(0.f,0.f,0.f,0.f);
    for(size_t i=(size_t)bid*256+tid; i<n4; i+=(size_t)256*256)
      dst[i]=z4;
  }
}

// ---------------- exclusive scan of histogram -> offsets + total count ----------------
__global__ void k_scan(float* __restrict__ ws, int NR){
  __shared__ int sd[2048];
  int t=threadIdx.x;
  int* hist=(int*)(ws+OFF_HIST);
  int* offs=(int*)(ws+OFF_OFFS);
  int i1=t, i2=t+1024;
  sd[i1]=(i1<NR)? hist[i1]:0;
  sd[i2]=(i2<NR)? hist[i2]:0;
  __syncthreads();
  for(int d=1; d<2048; d<<=1){
    int v1=(i1>=d)? sd[i1-d]:0;
    int v2=(i2>=d)? sd[i2-d]:0;
    __syncthreads();
    sd[i1]+=v1; sd[i2]+=v2;
    __syncthreads();
  }
  if(i1<NR) offs[i1]=(i1==0)?0:sd[i1-1];
  if(i2<NR) offs[i2]=sd[i2-1];
  if(t==0){ offs[NR]=sd[NR-1]; *((int*)(ws+OFF_CNT))=sd[NR-1]; }
}

// ---------------- scatter active edges into r-sorted EINFO ----------------
__global__ void k_scatter(const int* __restrict__ esrc, const int* __restrict__ edst,
                          float* __restrict__ ws, int NR){
  int e=blockIdx.x*256+threadIdx.x;
  if(e>=NEDGE) return;
  float r=ws[OFF_RBUF+e];
  if(!(r>0.5f && r<2.5f)) return;
  float t=(r-0.5f)*((float)NR*0.5f);
  int i0=min((int)t, NR-1);
  int* offs=(int*)(ws+OFF_OFFS);
  int* cur=(int*)(ws+OFF_CUR);
  int p=offs[i0]+atomicAdd(&cur[i0],1);
  int4 v; v.x=esrc[e]; v.y=edst[e]; v.z=e; v.w=__float_as_int(t);
  ((int4*)(ws+OFF_EINFO))[p]=v;
}

// ---------------- fused conv: gate(on input) + table-lerp weights + tensor product + scatter ----------------
template<int CONV,int DY,int D_IN,int D_OUT,int CSTRIDE,int NCOL,int NCOLS,bool FINAL>
__global__ __launch_bounds__(256,4) void k_conv(
    const float* __restrict__ xin, const float* __restrict__ TAB,
    float* __restrict__ yout, const int* __restrict__ batchp,
    float* __restrict__ ws, int NR)
{
  constexpr int APAD = D_IN+4;
  constexpr int NGP  = (CONV==2)?36:4;
  constexpr int YST  = (CONV==3)?132:4;
  constexpr int NGV  = (CONV==2)?32:((CONV==3)?24:1);
  __shared__ float sh_a[8][APAD];
  __shared__ float sh_b[8][20];
  __shared__ float sh_core[8][CSTRIDE];
  __shared__ float sh_g[8][NGP];
  __shared__ float sh_gv[8][NGV];
  __shared__ float sh_y[8][YST];
  __shared__ float sh_red[8];
  __shared__ int sh_src[8], sh_dst[8], sh_eid[8];
  __shared__ float sh_t[8];

  int tid=threadIdx.x;
  int nact=*(const int*)(ws+OFF_CNT);
  int base=blockIdx.x*8;
  if(base>=nact) return;
  int ne=min(8, nact-base);

  if(tid<8){
    int src=0,dst=0,eid=-1; float tv=0.0f;
    if(tid<ne){
      int4 v=((const int4*)(ws+OFF_EINFO))[base+tid];
      src=v.x; dst=v.y; eid=v.z; tv=__int_as_float(v.w);
    }
    sh_src[tid]=src; sh_dst[tid]=dst; sh_eid[tid]=eid; sh_t[tid]=tv;
    if constexpr(CONV==3) sh_red[tid]=0.0f;
  }
  __syncthreads();

  // stage b (8 x 16 floats) via float4
  if(tid<32){
    int idx=tid>>2, c4=tid&3;
    int eid=sh_eid[idx];
    float4 v=make_float4(0.f,0.f,0.f,0.f);
    if(eid>=0) v=((const float4*)(ws+OFF_EATTR+(size_t)eid*16))[c4];
    *(float4*)&sh_b[idx][c4*4]=v;
  }
  // stage a (conv1) or raw y (conv2/3)
  if constexpr(CONV==1){
    if(tid>=32 && tid<64){
      int t2=tid-32; int idx=t2>>2, c4=t2&3;
      float4 v=make_float4(0.f,0.f,0.f,0.f);
      if(sh_eid[idx]>=0) v=((const float4*)(xin+(size_t)sh_src[idx]*16))[c4];
      *(float4*)&sh_a[idx][c4*4]=v;
    }
  } else {
    constexpr int YQ=DY/4;
    for(int z=tid; z<8*YQ; z+=256){
      int idx=z/YQ, c4=z-idx*YQ;
      float4 v=make_float4(0.f,0.f,0.f,0.f);
      if(sh_eid[idx]>=0) v=((const float4*)(xin+(size_t)sh_src[idx]*DY))[c4];
      if constexpr(CONV==2) *(float4*)&sh_core[idx][c4*4]=v;   // park y in sh_core area
      else                  *(float4*)&sh_y[idx][c4*4]=v;
    }
  }
  __syncthreads();

  // ---- gate + core contraction ----
  if constexpr(CONV==1){
    constexpr int NIT=31;
    for(int z=tid; z<8*NIT; z+=256){
      int idx=z/NIT, rem=z-idx*NIT;
      CItem it=CIT1.it[rem];
      float acc=0.0f;
      for(int i=0;i<it.n1;i++){
        float av=sh_a[idx][it.aoff+i];
        int cb=it.cofs + i*it.n2*it.jstep;
        for(int j=0;j<it.n2;j++)
          acc += av*sh_b[idx][it.boff+j]*W3JC.v[cb + j*it.jstep];
      }
      sh_core[idx][it.woff]=acc;
    }
    __syncthreads();
  } else {
    float TN=ws[OFF_TANH];
    // phase A: gate scalars (once per edge) + g-phase (b-contraction)
    for(int z=tid; z<8*NGV; z+=256){
      int idx=z/NGV, m=z-idx*NGV;
      const float* yr=(CONV==2)? &sh_core[idx][0] : &sh_y[idx][0];
      float u=yr[32+m];
      bool th=(CONV==2)? (((m>>3)&1)!=0) : (((m/6)&1)!=0);
      sh_gv[idx][m]= th? tanhf(u)*TN : fmaxf(u,0.0f)*SQRT2F;
    }
    constexpr int NG=(CONV==2)?34:4;
    for(int z=tid; z<8*NG; z+=256){
      int idx=z/NG, rem=z-idx*NG;
      GItem it=(CONV==2)? GIT2.it[rem] : GIT3.it[rem];
      float acc=0.0f;
      for(int j=0;j<it.n2;j++)
        acc += sh_b[idx][it.boff+j]*W3JC.v[it.cofs + j*it.jstep];
      sh_g[idx][rem]=acc;
    }
    __syncthreads();
    // phase B: gate-main -> sh_a
    for(int z=tid; z<8*D_IN; z+=256){
      int idx=z/D_IN, o=z-idx*D_IN;
      const float* yr=(CONV==2)? &sh_core[idx][0] : &sh_y[idx][0];
      float val;
      if(o<16) val=fmaxf(yr[o],0.0f)*SQRT2F;
      else if(o<32) val=fabsf(yr[o]);
      else {
        if constexpr(CONV==2){
          int gi=(o<80)? (o-32)/3 : 16+(o-80)/3;
          val=yr[o+32]*sh_gv[idx][gi];
        } else {
          int gi=(o<68)? (o-32)/3 : 12+(o-68)/3;
          val=yr[o+24]*sh_gv[idx][gi];
        }
      }
      sh_a[idx][o]=val;
    }
    __syncthreads();
    // phase C: O-phase (overwrites sh_core; y no longer needed)
    constexpr int NO=(CONV==2)?448:44;
    for(int z=tid; z<8*NO; z+=256){
      int idx=z/NO, rem=z-idx*NO;
      OItem it=(CONV==2)? OIT2.it[rem] : OIT3.it[rem];
      float acc=0.0f;
      #pragma unroll 3
      for(int i=0;i<it.n1;i++)
        acc += sh_a[idx][it.aoff+i]*sh_g[idx][it.gofs + i*it.n3];
      sh_core[idx][it.woff]=acc;
    }
    __syncthreads();
  }

  // ---- apply ----
  if constexpr(CONV==3){
    if(tid<88){
      int e3=tid&7, c=tid>>3;
      float tv=sh_t[e3];
      int i0=min((int)tv, NR-1);
      float fr=tv-(float)i0;
      const float* tj=TAB+(size_t)i0*NCOLS + c*4;
      float4 w0=*(const float4*)tj;
      float4 w1=*(const float4*)(tj+NCOLS);
      float4 cv=*(const float4*)(&sh_core[e3][c*4]);
      float p;
      p  = (w0.x+fr*(w1.x-w0.x))*cv.x;
      p += (w0.y+fr*(w1.y-w0.y))*cv.y;
      p += (w0.z+fr*(w1.z-w0.z))*cv.z;
      p += (w0.w+fr*(w1.w-w0.w))*cv.w;
      atomicAdd(&sh_red[e3], p);
    }
    __syncthreads();
    if(tid<ne) atomicAdd(&ws[OFF_GSUM+batchp[sh_dst[tid]]], sh_red[tid]);
  } else {
    int e=tid&7;
    float tv=sh_t[e];
    int i0=min((int)tv, NR-1);
    float fr=tv-(float)i0;
    const float* T0=TAB+(size_t)i0*NCOLS;
    const float* crb=&sh_core[e][0];
    int dstv=sh_dst[e];
    bool act=(e<ne);

    for(int q=tid; q<8*NCOL; q+=256){
      int c=q>>3;
      int s0,s1,ob,n3;
      const Ent2* entp;
      if constexpr(CONV==1){ s0=CMETA1.cidx[c]; s1=CMETA1.cidx[c+1]; ob=CMETA1.obase[c]; n3=CMETA1.n3c[c]; entp=CMETA1.ent; }
      else                 { s0=CMETA2.cidx[c]; s1=CMETA2.cidx[c+1]; ob=CMETA2.obase[c]; n3=CMETA2.n3c[c]; entp=CMETA2.ent; }
      int cnt=s1-s0;
      if(!cnt) continue;
      float a0=0.0f,a1=0.0f,a2=0.0f;
      const Ent2* ep=entp+s0;
      if constexpr(CONV==1){
        if(n3==1){
          switch(cnt){
            case 4: apply1_col<4,1,272>(ep,T0,crb,fr,a0,a1,a2); break;
            default: apply1_dyn(ep,cnt,1,T0,crb,fr,272,a0,a1,a2); break;
          }
        } else {
          switch(cnt){
            case 6: apply1_col<6,3,272>(ep,T0,crb,fr,a0,a1,a2); break;
            case 3: apply1_col<3,3,272>(ep,T0,crb,fr,a0,a1,a2); break;
            default: apply1_dyn(ep,cnt,3,T0,crb,fr,272,a0,a1,a2); break;
          }
        }
      } else {
        if(n3==1){
          switch(cnt){
            case 3: apply2_col<3,1,3328>(ep,T0,crb,fr,a0,a1,a2); break;
            case 1: apply2_col<1,1,3328>(ep,T0,crb,fr,a0,a1,a2); break;
            default: apply2_dyn(ep,cnt,1,T0,crb,fr,3328,a0,a1,a2); break;
          }
        } else {
          switch(cnt){
            case 5: apply2_col<5,3,3328>(ep,T0,crb,fr,a0,a1,a2); break;
            case 3: apply2_col<3,3,3328>(ep,T0,crb,fr,a0,a1,a2); break;
            default: apply2_dyn(ep,cnt,3,T0,crb,fr,3328,a0,a1,a2); break;
          }
        }
      }
      if(act){
        float* yp=&yout[(size_t)dstv*D_OUT+ob];
        atomicAdd(yp, a0);
        if(n3==3){ atomicAdd(yp+1, a1); atomicAdd(yp+2, a2); }
      }
    }
  }
}

__global__ void k_sig(const float* __restrict__ ws, float* __restrict__ out){
  int g=threadIdx.x;
  if(g<NGRAPH){
    float v=ws[OFF_GSUM+g];
    out[g]=1.0f/(1.0f+expf(-v));
  }
}

// ---------------- launch ----------------
extern "C" void kernel_launch(void* const* d_in, const int* in_sizes, int n_in,
                              void* d_out, int out_size, void* d_ws, size_t ws_size,
                              hipStream_t stream){
  const float* pos =(const float*)d_in[0];
  const float* w1_1=(const float*)d_in[1];
  const float* w2_1=(const float*)d_in[2];
  const float* w1_2=(const float*)d_in[3];
  const float* w2_2=(const float*)d_in[4];
  const float* w1_3=(const float*)d_in[5];
  const float* w2_3=(const float*)d_in[6];
  const int* esrc=(const int*)d_in[7];
  const int* edst=(const int*)d_in[8];
  const int* batch=(const int*)d_in[9];
  float* ws=(float*)d_ws;
  float* out=(float*)d_out;

  // table resolution adapted to available workspace (rows = NR+1)
  long availRows = ((long)(ws_size/4) - (long)OFF_TAB)/3644L;
  int R = (availRows < 1025L)? (int)availRows : 1025;
  if(R < 9) R = 9;
  int NR = R-1;
  int NXT = (R+7)/8;
  float* TAB1 = ws + OFF_TAB;
  float* TAB2 = TAB1 + (size_t)R*272;
  float* TAB3 = TAB2 + (size_t)R*3328;

  // zero: cnt/gsum, hist/offs/cur, x0 (needed BEFORE k_front's edge atomics);
  // Y1/Y2 zeroing is folded into k_front (consumed only by later conv launches)
  hipMemsetAsync(ws+OFF_CNT, 0, (size_t)(728-OFF_CNT)*sizeof(float), stream);
  hipMemsetAsync(ws+OFF_HIST, 0, (size_t)(13832-OFF_HIST)*sizeof(float), stream);
  hipMemsetAsync(ws+OFF_X0, 0, (size_t)(OFF_Y1-OFF_X0)*sizeof(float), stream);

  int nblk = 9*NXT + 1 + 313 + 256;
  k_front<<<nblk,256,0,stream>>>(
      w1_1,w2_1,TAB1, w1_2,w2_2,TAB2, w1_3,w2_3,TAB3,
      pos, esrc, edst, R, NR, NXT, ws);
  k_scan<<<1,1024,0,stream>>>(ws, NR);
  k_scatter<<<(NEDGE+255)/256,256,0,stream>>>(esrc, edst, ws, NR);

  k_conv<1, 16, 16,160, 33, 96, 272,false><<<(NEDGE+7)/8,256,0,stream>>>(
      ws+OFF_X0, TAB1, ws+OFF_Y1, batch, ws, NR);

  k_conv<2,160,128,128,452, 80,3328,false><<<(NEDGE+7)/8,256,0,stream>>>(
      ws+OFF_Y1, TAB2, ws+OFF_Y2, batch, ws, NR);

  k_conv<3,128,104,  1, 68,  1, 44,true ><<<(NEDGE+7)/8,256,0,stream>>>(
      ws+OFF_Y2, TAB3, nullptr, batch, ws, NR);

  k_sig<<<1,64,0,stream>>>(ws, out);
}